// Round 2
// baseline (16549.460 us; speedup 1.0000x reference)
//
#include <hip/hip_runtime.h>
#include <math.h>

#define NEGF (-1e9f)

constexpr int NT = 1024;             // tokens
constexpr int D  = 768;
constexpr int SW = 30;               // max span width
constexpr int NC = NT * SW;          // 30720 candidates
constexpr int FT = 20;
constexpr int FF = 1000;
constexpr int TOPN = 409;            // int(0.4*1024)
constexpr int KA = 50;
constexpr int SD = 2 * D + FT + D;   // 2324
constexpr int PD = 3 * SD + 4 * FT;  // 7052
constexpr int MP = TOPN * KA;        // 20450

// ---- ws layout (float units) ----
constexpr size_t O_TOKATT = 0;                                  // 1024 f
constexpr size_t O_WPS    = O_TOKATT + 1024;                    // 32 f
constexpr size_t O_DPR    = O_WPS + 32;                         // 16 f
constexpr size_t O_CNT    = O_DPR + 16;                         // 16 i
constexpr size_t O_VLIST  = O_CNT + 16;                         // NC i
constexpr size_t O_VPOS   = O_VLIST + NC;                       // NC i
constexpr size_t O_MENT   = O_VPOS + NC;                        // NC f
constexpr size_t O_TIDX   = O_MENT + NC;                        // 512 i
constexpr size_t O_TST    = O_TIDX + 512;                       // 512 i
constexpr size_t O_TEN    = O_TST + 512;                        // 512 i
constexpr size_t O_TME    = O_TEN + 512;                        // 512 f
constexpr size_t O_TEMB   = O_TME + 512;                        // TOPN*SD f
constexpr size_t O_TMPB   = O_TEMB + (size_t)TOPN * SD;         // TOPN*(SD+1) f
constexpr size_t O_COARSE = O_TMPB + (size_t)TOPN * (SD + 1);   // TOPN*TOPN f
constexpr size_t O_ANTI   = O_COARSE + (size_t)TOPN * TOPN;     // 20480 i
constexpr size_t O_ANTC   = O_ANTI + 20480;                     // 20480 f
constexpr size_t O_FEAT   = O_ANTC + 20480;                     // MP*80 f
constexpr size_t O_SLOW   = O_FEAT + (size_t)MP * 80;           // 20480 f
constexpr size_t O_HEAD   = O_SLOW + 20480;                     // NC*D f (only valid rows written)

__device__ __forceinline__ unsigned int f2sort(float f) {
    unsigned int u = __float_as_uint(f);
    return (u & 0x80000000u) ? ~u : (u | 0x80000000u);
}
__device__ __forceinline__ int bucket_dist(int d) {   // d >= 0
    if (d <= 4) return d;
    return min(34 - __clz(d), 9);                     // floor(log2(d)) + 3, clipped
}

// ---------------- small prep kernels ----------------
__global__ void k_init(const float* b_p2, float* slow, int* cnt) {
    int i = blockIdx.x * 256 + threadIdx.x;
    if (i < MP) slow[i] = b_p2[0];
    if (i == 0) cnt[0] = 0;
}

__global__ void k_tokatt(const float* emb, const float* w, const float* b, float* out) {
    int wave = threadIdx.x >> 6, lane = threadIdx.x & 63;
    int tok = blockIdx.x * 4 + wave;
    float s = 0.f;
    for (int d = lane; d < D; d += 64) s += emb[tok * D + d] * w[d];
    for (int o = 32; o; o >>= 1) s += __shfl_down(s, o);
    if (lane == 0) out[tok] = s + b[0];
}

__global__ void k_widthps(const float* e, const float* w1, const float* b1,
                          const float* w2, const float* b2, float* out) {
    int wi = blockIdx.x;
    float acc = 0.f;
    for (int n = threadIdx.x; n < FF; n += 256) {
        float h = b1[n];
        for (int f = 0; f < FT; ++f) h += e[wi * FT + f] * w1[f * FF + n];
        acc += fmaxf(h, 0.f) * w2[n];
    }
    __shared__ float red[256];
    red[threadIdx.x] = acc; __syncthreads();
    for (int s = 128; s; s >>= 1) {
        if (threadIdx.x < s) red[threadIdx.x] += red[threadIdx.x + s];
        __syncthreads();
    }
    if (threadIdx.x == 0) out[wi] = red[0] + b2[0];
}

__global__ void k_distpr(const float* e, const float* w, const float* b, float* out) {
    int d = threadIdx.x;
    if (d < 10) {
        float s = b[0];
        for (int f = 0; f < FT; ++f) s += e[d * FT + f] * w[f];
        out[d] = s;
    }
}

__global__ void k_valid(const int* sentmap, const float* wps, const float* b_s2,
                        float* ment, int* vlist, int* vpos, int* cnt) {
    int c = blockIdx.x * 256 + threadIdx.x;
    if (c >= NC) return;
    int st = c / SW, wd = c % SW;
    int e_raw = st + wd;
    int e = min(e_raw, NT - 1);
    bool val = (e_raw < NT) && (sentmap[st] == sentmap[e]);
    ment[c] = val ? (wps[wd] + b_s2[0]) : NEGF;
    if (val) {
        int p = atomicAdd(cnt, 1);
        vlist[p] = c;
        vpos[c] = p;
    }
}

// one block (256 thr) per valid span: masked softmax over span tokens -> head emb
__global__ void k_head(const float* emb, const float* tokatt, const int* vlist,
                       const int* cnt, float* head) {
    int v = blockIdx.x;
    if (v >= cnt[0]) return;
    int c = vlist[v];
    int st = c / SW, wd = c % SW;
    int e = min(st + wd, NT - 1);
    int len = e - st + 1;                       // <= 30
    __shared__ float p[32];
    int tid = threadIdx.x;
    if (tid < len) p[tid] = tokatt[st + tid];
    __syncthreads();
    if (tid == 0) {
        float m = p[0];
        for (int t = 1; t < len; ++t) m = fmaxf(m, p[t]);
        float s = 0.f;
        for (int t = 0; t < len; ++t) { p[t] = expf(p[t] - m); s += p[t]; }
        float inv = 1.f / s;
        for (int t = 0; t < len; ++t) p[t] *= inv;
    }
    __syncthreads();
    for (int d = tid; d < D; d += 256) {
        float a = 0.f;
        for (int t = 0; t < len; ++t) a += p[t] * emb[(st + t) * D + d];
        head[(size_t)v * D + d] = a;
    }
}

// ---------------- fused mention FFNN GEMM ----------------
// A[v][k] built on the fly (start|end|width|head), B = w_span1 [SD][FF].
// layer-2 fused: partial = sum_n relu(h+b1)*w2 -> atomicAdd(ment[c]).
__global__ __launch_bounds__(256) void k_ment_gemm(
    const float* emb, const float* wemb, const float* head,
    const float* w1, const float* b1, const float* w2,
    const int* vlist, const int* cnt, float* ment) {
    int Nv = cnt[0];
    int m0 = blockIdx.x * 64, n0 = blockIdx.y * 64;
    if (m0 >= Nv) return;
    __shared__ float As[32][65], Bs[32][65];
    int tid = threadIdx.x;
    int tx = tid & 15, ty = tid >> 4;
    float acc[4][4] = {};
    for (int k0 = 0; k0 < SD; k0 += 32) {
        for (int i = 0; i < 8; ++i) {
            int lid = tid + i * 256;
            int r = lid >> 5, kk = lid & 31;
            int v = m0 + r, k = k0 + kk;
            float val = 0.f;
            if (v < Nv && k < SD) {
                int c = vlist[v];
                int st = c / SW, wd = c % SW;
                if (k < D) val = emb[st * D + k];
                else if (k < 2 * D) { int e = min(st + wd, NT - 1); val = emb[e * D + (k - D)]; }
                else if (k < 2 * D + FT) val = wemb[wd * FT + (k - 2 * D)];
                else val = head[(size_t)v * D + (k - 2 * D - FT)];
            }
            As[kk][r] = val;
        }
        for (int i = 0; i < 8; ++i) {
            int lid = tid + i * 256;
            int r = lid >> 6, nn = lid & 63;
            int k = k0 + r, n = n0 + nn;
            Bs[r][nn] = (k < SD && n < FF) ? w1[(size_t)k * FF + n] : 0.f;
        }
        __syncthreads();
        for (int kk = 0; kk < 32; ++kk) {
            float a[4], b[4];
            for (int i = 0; i < 4; ++i) a[i] = As[kk][ty * 4 + i];
            for (int j = 0; j < 4; ++j) b[j] = Bs[kk][tx * 4 + j];
            for (int i = 0; i < 4; ++i)
                for (int j = 0; j < 4; ++j) acc[i][j] += a[i] * b[j];
        }
        __syncthreads();
    }
    __shared__ float red[16][65];
    for (int i = 0; i < 4; ++i) {
        float t = 0.f;
        for (int j = 0; j < 4; ++j) {
            int n = n0 + tx * 4 + j;
            if (n < FF) t += fmaxf(acc[i][j] + b1[n], 0.f) * w2[n];
        }
        red[tx][ty * 4 + i] = t;
    }
    __syncthreads();
    if (tid < 64) {
        int v = m0 + tid;
        if (v < Nv) {
            float t = 0.f;
            for (int x = 0; x < 16; ++x) t += red[x][tid];
            atomicAdd(&ment[vlist[v]], t);
        }
    }
}

// ---------------- top-409 selection (single block) ----------------
__global__ __launch_bounds__(1024) void k_topk(const float* ment, int* topidx) {
    __shared__ unsigned int hist[256];
    __shared__ unsigned int sc[1024];
    __shared__ unsigned int sh_prefix, sh_needed, sh_run, sh_base2, sh_rune;
    int tid = threadIdx.x;
    if (tid == 0) { sh_prefix = 0; sh_needed = TOPN; }
    for (int r = 3; r >= 0; --r) {
        if (tid < 256) hist[tid] = 0;
        __syncthreads();
        unsigned int pref = sh_prefix;
        for (int c = tid; c < NC; c += 1024) {
            unsigned int u = f2sort(ment[c]);
            bool match = (r == 3) || ((u >> ((r + 1) * 8)) == pref);
            if (match) atomicAdd(&hist[(u >> (r * 8)) & 255u], 1u);
        }
        __syncthreads();
        if (tid == 0) {
            unsigned int need = sh_needed, cum = 0; int sel = 0;
            for (int b = 255; b >= 0; --b) {
                if (cum + hist[b] >= need) { sel = b; sh_needed = need - cum; break; }
                cum += hist[b];
            }
            sh_prefix = (sh_prefix << 8) | (unsigned int)sel;
        }
        __syncthreads();
    }
    unsigned int kth = sh_prefix;
    unsigned int quota = sh_needed;     // # of tied keys to take (lowest index first)
    if (tid == 0) sh_run = 0;
    __syncthreads();
    // keys strictly greater, in ascending index order
    for (int base = 0; base < NC; base += 1024) {
        int c = base + tid;
        unsigned int u = f2sort(ment[c]);
        unsigned int flag = (u > kth) ? 1u : 0u;
        sc[tid] = flag; __syncthreads();
        for (int off = 1; off < 1024; off <<= 1) {
            unsigned int v = (tid >= off) ? sc[tid - off] : 0u;
            __syncthreads();
            sc[tid] += v;
            __syncthreads();
        }
        if (flag) topidx[sh_run + sc[tid] - 1] = c;
        unsigned int tot = sc[1023];
        __syncthreads();
        if (tid == 0) sh_run += tot;
        __syncthreads();
    }
    if (tid == 0) { sh_base2 = sh_run; sh_rune = 0; }
    __syncthreads();
    // tied keys, first `quota` by index
    for (int base = 0; base < NC; base += 1024) {
        int c = base + tid;
        unsigned int u = f2sort(ment[c]);
        unsigned int flag = (u == kth) ? 1u : 0u;
        sc[tid] = flag; __syncthreads();
        for (int off = 1; off < 1024; off <<= 1) {
            unsigned int v = (tid >= off) ? sc[tid - off] : 0u;
            __syncthreads();
            sc[tid] += v;
            __syncthreads();
        }
        if (flag && (sh_rune + sc[tid] - 1) < quota)
            topidx[sh_base2 + sh_rune + sc[tid] - 1] = c;
        unsigned int tot = sc[1023];
        __syncthreads();
        if (tid == 0) sh_rune += tot;
        __syncthreads();
    }
    // bitonic sort 512 (pad INT_MAX) -> ascending indices
    __shared__ int arr[512];
    if (tid < 512) arr[tid] = (tid < TOPN) ? topidx[tid] : 0x7fffffff;
    __syncthreads();
    for (int k = 2; k <= 512; k <<= 1) {
        for (int j = k >> 1; j > 0; j >>= 1) {
            if (tid < 512) {
                int i = tid, p = i ^ j;
                if (p > i) {
                    bool asc = ((i & k) == 0);
                    int a = arr[i], b = arr[p];
                    if ((a > b) == asc) { arr[i] = b; arr[p] = a; }
                }
            }
            __syncthreads();
        }
    }
    if (tid < TOPN) topidx[tid] = arr[tid];
}

// gather top spans: emb rows, starts/ends/ment; also emit start/end outputs
__global__ void k_gather(const float* emb, const float* wemb, const float* head,
                         const float* ment, const int* topidx, const int* vpos,
                         int* tst, int* ten, float* tme, float* temb,
                         float* out_s, float* out_e) {
    int t = blockIdx.x;
    int c = topidx[t];
    int st = c / SW, wd = c % SW;
    int e = min(st + wd, NT - 1);
    int v = vpos[c];
    for (int k = threadIdx.x; k < SD; k += 256) {
        float val;
        if (k < D) val = emb[st * D + k];
        else if (k < 2 * D) val = emb[e * D + (k - D)];
        else if (k < 2 * D + FT) val = wemb[wd * FT + (k - 2 * D)];
        else val = head[(size_t)v * D + (k - 2 * D - FT)];
        temb[(size_t)t * SD + k] = val;
    }
    if (threadIdx.x == 0) {
        tst[t] = st; ten[t] = e; tme[t] = ment[c];
        out_s[t] = (float)st; out_e[t] = (float)e;
    }
}

// ---------------- biaffine ----------------
// tmp = temb @ w_bi  [TOPN, SD+1]
__global__ __launch_bounds__(256) void k_biaff1(const float* temb, const float* wb, float* tmp) {
    int m0 = blockIdx.x * 64, n0 = blockIdx.y * 64;
    __shared__ float As[32][65], Bs[32][65];
    int tid = threadIdx.x, tx = tid & 15, ty = tid >> 4;
    float acc[4][4] = {};
    for (int k0 = 0; k0 < SD; k0 += 32) {
        for (int i = 0; i < 8; ++i) {
            int lid = tid + i * 256;
            int r = lid >> 5, kk = lid & 31;
            int m = m0 + r, k = k0 + kk;
            As[kk][r] = (m < TOPN && k < SD) ? temb[(size_t)m * SD + k] : 0.f;
        }
        for (int i = 0; i < 8; ++i) {
            int lid = tid + i * 256;
            int r = lid >> 6, nn = lid & 63;
            int k = k0 + r, n = n0 + nn;
            Bs[r][nn] = (k < SD && n < SD + 1) ? wb[(size_t)k * (SD + 1) + n] : 0.f;
        }
        __syncthreads();
        for (int kk = 0; kk < 32; ++kk) {
            float a[4], b[4];
            for (int i = 0; i < 4; ++i) a[i] = As[kk][ty * 4 + i];
            for (int j = 0; j < 4; ++j) b[j] = Bs[kk][tx * 4 + j];
            for (int i = 0; i < 4; ++i)
                for (int j = 0; j < 4; ++j) acc[i][j] += a[i] * b[j];
        }
        __syncthreads();
    }
    for (int i = 0; i < 4; ++i)
        for (int j = 0; j < 4; ++j) {
            int m = m0 + ty * 4 + i, n = n0 + tx * 4 + j;
            if (m < TOPN && n < SD + 1) tmp[(size_t)m * (SD + 1) + n] = acc[i][j];
        }
}

// coarse[x][y] = tmp[x,:SD].temb[y] + tmp[x,SD] + ment sums + mask + dist prior
__global__ __launch_bounds__(256) void k_biaff2(const float* tmp, const float* temb,
                                                const float* tme, const float* dpr,
                                                float* coarse) {
    int m0 = blockIdx.x * 64, n0 = blockIdx.y * 64;
    __shared__ float As[32][65], Bs[32][65];
    int tid = threadIdx.x, tx = tid & 15, ty = tid >> 4;
    float acc[4][4] = {};
    for (int k0 = 0; k0 < SD; k0 += 32) {
        for (int i = 0; i < 8; ++i) {
            int lid = tid + i * 256;
            int r = lid >> 5, kk = lid & 31;
            int m = m0 + r, k = k0 + kk;
            As[kk][r] = (m < TOPN && k < SD) ? tmp[(size_t)m * (SD + 1) + k] : 0.f;
        }
        for (int i = 0; i < 8; ++i) {
            int lid = tid + i * 256;
            int y = lid >> 5, kk = lid & 31;
            int n = n0 + y, k = k0 + kk;
            Bs[kk][y] = (n < TOPN && k < SD) ? temb[(size_t)n * SD + k] : 0.f;
        }
        __syncthreads();
        for (int kk = 0; kk < 32; ++kk) {
            float a[4], b[4];
            for (int i = 0; i < 4; ++i) a[i] = As[kk][ty * 4 + i];
            for (int j = 0; j < 4; ++j) b[j] = Bs[kk][tx * 4 + j];
            for (int i = 0; i < 4; ++i)
                for (int j = 0; j < 4; ++j) acc[i][j] += a[i] * b[j];
        }
        __syncthreads();
    }
    for (int i = 0; i < 4; ++i)
        for (int j = 0; j < 4; ++j) {
            int x = m0 + ty * 4 + i, y = n0 + tx * 4 + j;
            if (x < TOPN && y < TOPN) {
                float val = acc[i][j] + tmp[(size_t)x * (SD + 1) + SD] + tme[x] + tme[y];
                int off = x - y;
                val += (off >= 1) ? 0.f : NEGF;
                val += dpr[bucket_dist(max(off, 0))];
                coarse[(size_t)x * TOPN + y] = val;
            }
        }
}

// per-row top-50 (value desc, index asc tie-break) via iterative packed argmax
__global__ __launch_bounds__(256) void k_topant(const float* coarse, int* anti,
                                                float* antc, float* out_ai) {
    int x = blockIdx.x;
    int tid = threadIdx.x;
    __shared__ float vals[512];
    __shared__ unsigned long long red[256];
    vals[tid] = (tid < TOPN) ? coarse[(size_t)x * TOPN + tid] : -INFINITY;
    vals[tid + 256] = (tid + 256 < TOPN) ? coarse[(size_t)x * TOPN + tid + 256] : -INFINITY;
    __syncthreads();
    for (int j = 0; j < KA; ++j) {
        unsigned long long best = 0ull;
        for (int h = 0; h < 2; ++h) {
            int y = tid + h * 256;
            unsigned long long p = ((unsigned long long)f2sort(vals[y]) << 32)
                                 | (unsigned long long)(0xFFFFFFFFu - (unsigned int)y);
            if (p > best) best = p;
        }
        red[tid] = best; __syncthreads();
        for (int s = 128; s; s >>= 1) {
            if (tid < s) { if (red[tid + s] > red[tid]) red[tid] = red[tid + s]; }
            __syncthreads();
        }
        if (tid == 0) {
            unsigned long long r = red[0];
            int y = (int)(0xFFFFFFFFu - (unsigned int)(r & 0xFFFFFFFFu));
            anti[x * KA + j] = y;
            antc[x * KA + j] = vals[y];
            out_ai[x * KA + j] = (float)y;
            vals[y] = -INFINITY;
        }
        __syncthreads();
    }
}

// pair features [MP][80]
__global__ void k_feat(const int* anti, const int* tst, const int* spk, const int* seg,
                       const int* genre, const float* e_same, const float* e_genre,
                       const float* e_seg, const float* e_antd, float* featb) {
    int idx = blockIdx.x * 256 + threadIdx.x;
    if (idx >= MP * 80) return;
    int m = idx / 80, f = idx % 80;
    int t = m / KA;
    int a = anti[m];
    float v;
    if (f < 20) {
        int ss = (spk[tst[t]] == spk[tst[a]]) ? 1 : 0;
        v = e_same[ss * FT + f];
    } else if (f < 40) {
        v = e_genre[genre[0] * FT + (f - 20)];
    } else if (f < 60) {
        int sd = seg[tst[t]] - seg[tst[a]];
        sd = min(max(sd, 0), 10);
        v = e_seg[sd * FT + (f - 40)];
    } else {
        int d2 = max(t - a, 0);
        v = e_antd[bucket_dist(d2) * FT + (f - 60)];
    }
    featb[idx] = v;
}

// ---------------- fused pair FFNN GEMM ----------------
// A[m][k]: src | tgt | src*tgt | feat, built on the fly. layer-2 fused like ment.
__global__ __launch_bounds__(256) void k_pair_gemm(
    const float* temb, const float* featb, const int* anti,
    const float* w1, const float* b1, const float* w2, float* slow) {
    int m0 = blockIdx.x * 64, n0 = blockIdx.y * 64;
    __shared__ float As[32][65], Bs[32][65];
    int tid = threadIdx.x, tx = tid & 15, ty = tid >> 4;
    float acc[4][4] = {};
    for (int k0 = 0; k0 < PD; k0 += 32) {
        for (int i = 0; i < 8; ++i) {
            int lid = tid + i * 256;
            int r = lid >> 5, kk = lid & 31;
            int m = m0 + r, k = k0 + kk;
            float val = 0.f;
            if (m < MP && k < PD) {
                int t = m / KA;
                int a = anti[m];
                if (k < SD) val = temb[(size_t)t * SD + k];
                else if (k < 2 * SD) val = temb[(size_t)a * SD + (k - SD)];
                else if (k < 3 * SD) {
                    int k2 = k - 2 * SD;
                    val = temb[(size_t)t * SD + k2] * temb[(size_t)a * SD + k2];
                } else val = featb[(size_t)m * 80 + (k - 3 * SD)];
            }
            As[kk][r] = val;
        }
        for (int i = 0; i < 8; ++i) {
            int lid = tid + i * 256;
            int r = lid >> 6, nn = lid & 63;
            int k = k0 + r, n = n0 + nn;
            Bs[r][nn] = (k < PD && n < FF) ? w1[(size_t)k * FF + n] : 0.f;
        }
        __syncthreads();
        for (int kk = 0; kk < 32; ++kk) {
            float a[4], b[4];
            for (int i = 0; i < 4; ++i) a[i] = As[kk][ty * 4 + i];
            for (int j = 0; j < 4; ++j) b[j] = Bs[kk][tx * 4 + j];
            for (int i = 0; i < 4; ++i)
                for (int j = 0; j < 4; ++j) acc[i][j] += a[i] * b[j];
        }
        __syncthreads();
    }
    __shared__ float red[16][65];
    for (int i = 0; i < 4; ++i) {
        float t = 0.f;
        for (int j = 0; j < 4; ++j) {
            int n = n0 + tx * 4 + j;
            if (n < FF) t += fmaxf(acc[i][j] + b1[n], 0.f) * w2[n];
        }
        red[tx][ty * 4 + i] = t;
    }
    __syncthreads();
    if (tid < 64) {
        int m = m0 + tid;
        if (m < MP) {
            float t = 0.f;
            for (int x = 0; x < 16; ++x) t += red[x][tid];
            atomicAdd(&slow[m], t);
        }
    }
}

__global__ void k_final(const int* anti, const float* slow, const float* antc, float* out_f) {
    int t = blockIdx.x, j = threadIdx.x;
    if (j < KA) {
        int a = anti[t * KA + j];
        float sc = (a < t) ? (slow[t * KA + j] + antc[t * KA + j]) : NEGF;
        out_f[t * (KA + 1) + 1 + j] = sc;
    }
    if (j == KA) out_f[t * (KA + 1)] = 0.f;
}

extern "C" void kernel_launch(void* const* d_in, const int* in_sizes, int n_in,
                              void* d_out, int out_size, void* d_ws, size_t ws_size,
                              hipStream_t stream) {
    const float* token_embs = (const float*)d_in[0];
    const int*   speaker    = (const int*)d_in[1];
    const int*   sentmap    = (const int*)d_in[2];
    const int*   segids     = (const int*)d_in[3];
    const int*   genre      = (const int*)d_in[4];
    const float* e_width    = (const float*)d_in[5];
    const float* e_width_pr = (const float*)d_in[6];
    const float* w_matt     = (const float*)d_in[7];
    const float* b_matt     = (const float*)d_in[8];
    const float* w_s1       = (const float*)d_in[9];
    const float* b_s1       = (const float*)d_in[10];
    const float* w_s2       = (const float*)d_in[11];
    const float* b_s2       = (const float*)d_in[12];
    const float* w_w1       = (const float*)d_in[13];
    const float* b_w1       = (const float*)d_in[14];
    const float* w_w2       = (const float*)d_in[15];
    const float* b_w2       = (const float*)d_in[16];
    const float* w_bi       = (const float*)d_in[17];
    const float* e_adp      = (const float*)d_in[18];
    const float* w_ad       = (const float*)d_in[19];
    const float* b_ad       = (const float*)d_in[20];
    const float* e_same     = (const float*)d_in[21];
    const float* e_genre    = (const float*)d_in[22];
    const float* e_seg      = (const float*)d_in[23];
    const float* e_antd     = (const float*)d_in[24];
    const float* w_p1       = (const float*)d_in[25];
    const float* b_p1       = (const float*)d_in[26];
    const float* w_p2       = (const float*)d_in[27];
    const float* b_p2       = (const float*)d_in[28];

    float* F = (float*)d_ws;
    float* tokatt = F + O_TOKATT;
    float* wps    = F + O_WPS;
    float* dpr    = F + O_DPR;
    int*   cnt    = (int*)(F + O_CNT);
    int*   vlist  = (int*)(F + O_VLIST);
    int*   vpos   = (int*)(F + O_VPOS);
    float* ment   = F + O_MENT;
    int*   tidx   = (int*)(F + O_TIDX);
    int*   tst    = (int*)(F + O_TST);
    int*   ten    = (int*)(F + O_TEN);
    float* tme    = F + O_TME;
    float* temb   = F + O_TEMB;
    float* tmpb   = F + O_TMPB;
    float* coarse = F + O_COARSE;
    int*   anti   = (int*)(F + O_ANTI);
    float* antc   = F + O_ANTC;
    float* featb  = F + O_FEAT;
    float* slow   = F + O_SLOW;
    float* head   = F + O_HEAD;

    float* out   = (float*)d_out;
    float* out_s = out;
    float* out_e = out + TOPN;
    float* out_ai = out + 2 * TOPN;
    float* out_f  = out + 2 * TOPN + MP;

    k_init<<<(MP + 255) / 256, 256, 0, stream>>>(b_p2, slow, cnt);
    k_tokatt<<<NT / 4, 256, 0, stream>>>(token_embs, w_matt, b_matt, tokatt);
    k_widthps<<<SW, 256, 0, stream>>>(e_width_pr, w_w1, b_w1, w_w2, b_w2, wps);
    k_distpr<<<1, 64, 0, stream>>>(e_adp, w_ad, b_ad, dpr);
    k_valid<<<NC / 256, 256, 0, stream>>>(sentmap, wps, b_s2, ment, vlist, vpos, cnt);
    k_head<<<NC, 256, 0, stream>>>(token_embs, tokatt, vlist, cnt, head);
    {
        dim3 g((NC + 63) / 64, (FF + 63) / 64);
        k_ment_gemm<<<g, 256, 0, stream>>>(token_embs, e_width, head, w_s1, b_s1, w_s2,
                                           vlist, cnt, ment);
    }
    k_topk<<<1, 1024, 0, stream>>>(ment, tidx);
    k_gather<<<TOPN, 256, 0, stream>>>(token_embs, e_width, head, ment, tidx, vpos,
                                       tst, ten, tme, temb, out_s, out_e);
    {
        dim3 g((TOPN + 63) / 64, (SD + 1 + 63) / 64);
        k_biaff1<<<g, 256, 0, stream>>>(temb, w_bi, tmpb);
    }
    {
        dim3 g((TOPN + 63) / 64, (TOPN + 63) / 64);
        k_biaff2<<<g, 256, 0, stream>>>(tmpb, temb, tme, dpr, coarse);
    }
    k_topant<<<TOPN, 256, 0, stream>>>(coarse, anti, antc, out_ai);
    k_feat<<<(MP * 80 + 255) / 256, 256, 0, stream>>>(anti, tst, speaker, segids, genre,
                                                      e_same, e_genre, e_seg, e_antd, featb);
    {
        dim3 g((MP + 63) / 64, (FF + 63) / 64);
        k_pair_gemm<<<g, 256, 0, stream>>>(temb, featb, anti, w_p1, b_p1, w_p2, slow);
    }
    k_final<<<TOPN, 64, 0, stream>>>(anti, slow, antc, out_f);
}

// Round 3
// 2112.079 us; speedup vs baseline: 7.8356x; 7.8356x over previous
//
#include <hip/hip_runtime.h>
#include <math.h>

#define NEGF (-1e9f)

constexpr int NT = 1024;             // tokens
constexpr int D  = 768;
constexpr int SW = 30;               // max span width
constexpr int NC = NT * SW;          // 30720 candidates
constexpr int FT = 20;
constexpr int FF = 1000;
constexpr int TOPN = 409;            // int(0.4*1024)
constexpr int KA = 50;
constexpr int SD = 2 * D + FT + D;   // 2324
constexpr int MP = TOPN * KA;        // 20450
constexpr int KP = 2336;             // SD padded to mult of 32
constexpr int NKT = KP / 32;         // 73

typedef short short8 __attribute__((ext_vector_type(8)));
typedef float f32x4 __attribute__((ext_vector_type(4)));

// ---- ws layout (float units), ~42 MB total ----
constexpr size_t al8(size_t x) { return (x + 7) & ~(size_t)7; }
constexpr size_t O_TOKATT = 0;                                     // 1024
constexpr size_t O_WPS    = al8(O_TOKATT + 1024);                  // 32
constexpr size_t O_DPR    = al8(O_WPS + 32);                       // 16
constexpr size_t O_MENT   = al8(O_DPR + 16);                       // NC
constexpr size_t O_TIDX   = al8(O_MENT + NC);                      // 512
constexpr size_t O_TST    = al8(O_TIDX + 512);
constexpr size_t O_TEN    = al8(O_TST + 512);
constexpr size_t O_TME    = al8(O_TEN + 512);
constexpr size_t O_TEMB   = al8(O_TME + 512);                      // 409*2324
constexpr size_t O_TMPB   = al8(O_TEMB + (size_t)TOPN * SD);       // 409*2325
constexpr size_t O_COARSE = al8(O_TMPB + (size_t)TOPN * (SD + 1)); // 409*409
constexpr size_t O_ANTI   = al8(O_COARSE + (size_t)TOPN * TOPN);   // 20480
constexpr size_t O_ANTC   = al8(O_ANTI + 20480);
constexpr size_t O_SLOW   = al8(O_ANTC + 20480);
constexpr size_t O_E      = al8(O_SLOW + 20480);                   // 1024*3072 (s|e|h)
constexpr size_t O_E2W    = al8(O_E + (size_t)NT * 3072);          // 30*1024
constexpr size_t O_PALL   = al8(O_E2W + 30 * 1024);                // 24*1024
constexpr size_t O_HST    = al8(O_PALL + 24 * 1024);               // 512*2048
constexpr size_t O_TEMBH  = al8(O_HST + (size_t)512 * 2048);       // 512*2336 bf16 -> /2 floats
constexpr size_t O_W1ST   = al8(O_TEMBH + (size_t)512 * KP / 2);   // 2048*2336 bf16
constexpr size_t O_W1P    = al8(O_W1ST + (size_t)2048 * KP / 2);   // 1024*2336 bf16

__device__ __forceinline__ unsigned int f2sort(float f) {
    unsigned int u = __float_as_uint(f);
    return (u & 0x80000000u) ? ~u : (u | 0x80000000u);
}
__device__ __forceinline__ int bucket_dist(int d) {   // d >= 0
    if (d <= 4) return d;
    return min(34 - __clz(d), 9);                     // floor(log2(d)) + 3, clipped
}
__device__ __forceinline__ unsigned short f2bf(float f) {   // RNE f32 -> bf16
    unsigned u = __float_as_uint(f);
    unsigned r = (u + 0x7fffu + ((u >> 16) & 1u)) >> 16;
    return (unsigned short)r;
}
__device__ __forceinline__ float bf2f(unsigned short s) {
    return __uint_as_float(((unsigned)s) << 16);
}

// ---------------- small prep kernels ----------------
__global__ void k_init(const float* b_p2, float* slow) {
    int i = blockIdx.x * 256 + threadIdx.x;
    if (i < MP) slow[i] = b_p2[0];
}

__global__ void k_tokatt(const float* emb, const float* w, const float* b, float* out) {
    int wave = threadIdx.x >> 6, lane = threadIdx.x & 63;
    int tok = blockIdx.x * 4 + wave;
    float s = 0.f;
    for (int d = lane; d < D; d += 64) s += emb[tok * D + d] * w[d];
    for (int o = 32; o; o >>= 1) s += __shfl_down(s, o);
    if (lane == 0) out[tok] = s + b[0];
}

__global__ void k_widthps(const float* e, const float* w1, const float* b1,
                          const float* w2, const float* b2, float* out) {
    int wi = blockIdx.x;
    float acc = 0.f;
    for (int n = threadIdx.x; n < FF; n += 256) {
        float h = b1[n];
        for (int f = 0; f < FT; ++f) h += e[wi * FT + f] * w1[f * FF + n];
        acc += fmaxf(h, 0.f) * w2[n];
    }
    __shared__ float red[256];
    red[threadIdx.x] = acc; __syncthreads();
    for (int s = 128; s; s >>= 1) {
        if (threadIdx.x < s) red[threadIdx.x] += red[threadIdx.x + s];
        __syncthreads();
    }
    if (threadIdx.x == 0) out[wi] = red[0] + b2[0];
}

__global__ void k_distpr(const float* e, const float* w, const float* b, float* out) {
    int d = threadIdx.x;
    if (d < 10) {
        float s = b[0];
        for (int f = 0; f < FT; ++f) s += e[d * FT + f] * w[f];
        out[d] = s;
    }
}

// E2W[wd][n] = sum_f e_width[wd][f] * w_s1[(1536+f)][n]
__global__ void k_e2w(const float* ew, const float* w1, float* e2w) {
    int idx = blockIdx.x * 256 + threadIdx.x;
    if (idx >= 30 * 1024) return;
    int wd = idx >> 10, n = idx & 1023;
    float s = 0.f;
    if (n < FF) for (int f = 0; f < FT; ++f) s += ew[wd * FT + f] * w1[(2 * D + f) * FF + n];
    e2w[idx] = s;
}

// Pall rows: 0-1 same-speaker, 2 genre + b_p1, 3..13 seg-dist, 14..23 ant-dist
__global__ void k_prep_pall(const float* w1, const float* b1, const int* genre,
                            const float* e_same, const float* e_genre,
                            const float* e_seg, const float* e_antd, float* pall) {
    int idx = blockIdx.x * 256 + threadIdx.x;
    if (idx >= 24 * 1024) return;
    int r = idx >> 10, n = idx & 1023;
    float s = 0.f;
    if (n < FF) {
        const float* tab; int foff;
        if (r < 2)       { tab = e_same + r * FT;          foff = 0; }
        else if (r == 2) { tab = e_genre + genre[0] * FT;  foff = FT; s = b1[n]; }
        else if (r < 14) { tab = e_seg + (r - 3) * FT;     foff = 2 * FT; }
        else             { tab = e_antd + (r - 14) * FT;   foff = 3 * FT; }
        for (int f = 0; f < FT; ++f) s += tab[f] * w1[(size_t)(3 * SD + foff + f) * FF + n];
    }
    pall[idx] = s;
}

// temb (fp32, 409xSD) -> tembh (bf16, 512xKP, zero-padded)
__global__ void k_cvt_temb(const float* temb, unsigned short* tembh) {
    int idx = blockIdx.x * 256 + threadIdx.x;
    if (idx >= 512 * KP) return;
    int t = idx / KP, k = idx % KP;
    float v = (t < TOPN && k < SD) ? temb[(size_t)t * SD + k] : 0.f;
    tembh[idx] = f2bf(v);
}

// w_p1 slices -> transposed bf16 [RN][KP]. mode 0: RN=2048 (src|tgt halves); mode 1: RN=1024 (prod)
__global__ void k_cvt_w1(const float* w1, unsigned short* dst, int mode) {
    __shared__ float tile[32][33];
    int kp0 = blockIdx.x * 32;
    int r0  = blockIdx.y * 32;
    int tx = threadIdx.x & 31, ty = threadIdx.x >> 5;
    for (int i = 0; i < 4; ++i) {
        int r = r0 + tx, kp = kp0 + ty + i * 8;
        int c, ro;
        if (mode == 0) { c = r & 1023; ro = (r >> 10) * SD; }
        else           { c = r;        ro = 2 * SD; }
        float v = (c < FF && kp < SD) ? w1[(size_t)(ro + kp) * FF + c] : 0.f;
        tile[ty + i * 8][tx] = v;
    }
    __syncthreads();
    for (int i = 0; i < 4; ++i) {
        int r = r0 + ty + i * 8, kp = kp0 + tx;
        dst[(size_t)r * KP + kp] = f2bf(tile[tx][ty + i * 8]);
    }
}

// ---------------- mention scores: per-start block, incremental attention ----------------
__global__ __launch_bounds__(256) void k_ment(
    const float* __restrict__ E, const float* __restrict__ e2w,
    const float* __restrict__ tokatt, const int* __restrict__ sentmap,
    const float* __restrict__ b1, const float* __restrict__ w2,
    const float* __restrict__ wps, const float* __restrict__ b_s2, float* ment) {
    int st = blockIdx.x;
    __shared__ float earr[32];
    __shared__ int vmask[32];
    __shared__ float swred[4][32];
    int tid = threadIdx.x;
    if (tid < SW) {
        int en = st + tid;
        bool ok = en < NT;
        earr[tid] = ok ? expf(tokatt[en]) : 0.f;
        vmask[tid] = ok && (sentmap[st] == sentmap[en]);
    }
    __syncthreads();
    int n4 = tid * 4;
    bool act = n4 < FF;
    float4 Es = {0,0,0,0}, B1 = {0,0,0,0}, W2 = {0,0,0,0};
    if (act) {
        Es = *(const float4*)(E + (size_t)st * 3072 + n4);
        B1 = *(const float4*)(b1 + n4);
        W2 = *(const float4*)(w2 + n4);
    }
    float Ux = 0, Uy = 0, Uz = 0, Uw = 0, S = 0.f;
    float part[SW];
    #pragma unroll
    for (int wd = 0; wd < SW; ++wd) {
        int en = st + wd;
        float p = 0.f;
        if (en < NT) {
            float e = earr[wd]; S += e;
            if (act) {
                float4 Eh = *(const float4*)(E + (size_t)en * 3072 + 2048 + n4);
                Ux += e * Eh.x; Uy += e * Eh.y; Uz += e * Eh.z; Uw += e * Eh.w;
                if (vmask[wd]) {
                    float inv = 1.f / S;
                    float4 Ee = *(const float4*)(E + (size_t)en * 3072 + 1024 + n4);
                    float4 Ww = *(const float4*)(e2w + wd * 1024 + n4);
                    float vx = Es.x + Ee.x + Ww.x + B1.x + Ux * inv;
                    float vy = Es.y + Ee.y + Ww.y + B1.y + Uy * inv;
                    float vz = Es.z + Ee.z + Ww.z + B1.z + Uz * inv;
                    float vw = Es.w + Ee.w + Ww.w + B1.w + Uw * inv;
                    p = fmaxf(vx, 0.f) * W2.x + fmaxf(vy, 0.f) * W2.y
                      + fmaxf(vz, 0.f) * W2.z + fmaxf(vw, 0.f) * W2.w;
                }
            }
        }
        part[wd] = p;
    }
    int lane = tid & 63, wv = tid >> 6;
    #pragma unroll
    for (int wd = 0; wd < SW; ++wd) {
        float r = part[wd];
        r += __shfl_xor(r, 1);  r += __shfl_xor(r, 2);  r += __shfl_xor(r, 4);
        r += __shfl_xor(r, 8);  r += __shfl_xor(r, 16); r += __shfl_xor(r, 32);
        if (lane == 0) swred[wv][wd] = r;
    }
    __syncthreads();
    if (tid < SW) {
        float tot = swred[0][tid] + swred[1][tid] + swred[2][tid] + swred[3][tid];
        ment[st * SW + tid] = vmask[tid] ? (tot + wps[tid] + b_s2[0]) : NEGF;
    }
}

// ---------------- top-409 selection (single block) ----------------
__global__ __launch_bounds__(1024) void k_topk(const float* ment, int* topidx) {
    __shared__ unsigned int hist[256];
    __shared__ unsigned int sc[1024];
    __shared__ unsigned int sh_prefix, sh_needed, sh_run, sh_base2, sh_rune;
    int tid = threadIdx.x;
    if (tid == 0) { sh_prefix = 0; sh_needed = TOPN; }
    for (int r = 3; r >= 0; --r) {
        if (tid < 256) hist[tid] = 0;
        __syncthreads();
        unsigned int pref = sh_prefix;
        for (int c = tid; c < NC; c += 1024) {
            unsigned int u = f2sort(ment[c]);
            bool match = (r == 3) || ((u >> ((r + 1) * 8)) == pref);
            if (match) atomicAdd(&hist[(u >> (r * 8)) & 255u], 1u);
        }
        __syncthreads();
        if (tid == 0) {
            unsigned int need = sh_needed, cum = 0; int sel = 0;
            for (int b = 255; b >= 0; --b) {
                if (cum + hist[b] >= need) { sel = b; sh_needed = need - cum; break; }
                cum += hist[b];
            }
            sh_prefix = (sh_prefix << 8) | (unsigned int)sel;
        }
        __syncthreads();
    }
    unsigned int kth = sh_prefix;
    unsigned int quota = sh_needed;
    if (tid == 0) sh_run = 0;
    __syncthreads();
    for (int base = 0; base < NC; base += 1024) {
        int c = base + tid;
        unsigned int u = f2sort(ment[c]);
        unsigned int flag = (u > kth) ? 1u : 0u;
        sc[tid] = flag; __syncthreads();
        for (int off = 1; off < 1024; off <<= 1) {
            unsigned int v = (tid >= off) ? sc[tid - off] : 0u;
            __syncthreads();
            sc[tid] += v;
            __syncthreads();
        }
        if (flag) topidx[sh_run + sc[tid] - 1] = c;
        unsigned int tot = sc[1023];
        __syncthreads();
        if (tid == 0) sh_run += tot;
        __syncthreads();
    }
    if (tid == 0) { sh_base2 = sh_run; sh_rune = 0; }
    __syncthreads();
    for (int base = 0; base < NC; base += 1024) {
        int c = base + tid;
        unsigned int u = f2sort(ment[c]);
        unsigned int flag = (u == kth) ? 1u : 0u;
        sc[tid] = flag; __syncthreads();
        for (int off = 1; off < 1024; off <<= 1) {
            unsigned int v = (tid >= off) ? sc[tid - off] : 0u;
            __syncthreads();
            sc[tid] += v;
            __syncthreads();
        }
        if (flag && (sh_rune + sc[tid] - 1) < quota)
            topidx[sh_base2 + sh_rune + sc[tid] - 1] = c;
        unsigned int tot = sc[1023];
        __syncthreads();
        if (tid == 0) sh_rune += tot;
        __syncthreads();
    }
    __shared__ int arr[512];
    if (tid < 512) arr[tid] = (tid < TOPN) ? topidx[tid] : 0x7fffffff;
    __syncthreads();
    for (int k = 2; k <= 512; k <<= 1) {
        for (int j = k >> 1; j > 0; j >>= 1) {
            if (tid < 512) {
                int i = tid, p = i ^ j;
                if (p > i) {
                    bool asc = ((i & k) == 0);
                    int a = arr[i], b = arr[p];
                    if ((a > b) == asc) { arr[i] = b; arr[p] = a; }
                }
            }
            __syncthreads();
        }
    }
    if (tid < TOPN) topidx[tid] = arr[tid];
}

// gather top spans; computes head-attn emb on the fly
__global__ void k_gather(const float* emb, const float* wemb, const float* tokatt,
                         const float* ment, const int* topidx,
                         int* tst, int* ten, float* tme, float* temb,
                         float* out_s, float* out_e) {
    int t = blockIdx.x;
    int c = topidx[t];
    int st = c / SW, wd = c % SW;
    int en = min(st + wd, NT - 1);
    int len = en - st + 1;
    __shared__ float p[32];
    if (threadIdx.x == 0) {
        float m = -1e30f;
        for (int j = 0; j < len; ++j) m = fmaxf(m, tokatt[st + j]);
        float s = 0.f;
        for (int j = 0; j < len; ++j) { p[j] = expf(tokatt[st + j] - m); s += p[j]; }
        float inv = 1.f / s;
        for (int j = 0; j < len; ++j) p[j] *= inv;
        tst[t] = st; ten[t] = en; tme[t] = ment[c];
        out_s[t] = (float)st; out_e[t] = (float)en;
    }
    __syncthreads();
    for (int k = threadIdx.x; k < SD; k += 256) {
        float val;
        if (k < D) val = emb[st * D + k];
        else if (k < 2 * D) val = emb[en * D + (k - D)];
        else if (k < 2 * D + FT) val = wemb[wd * FT + (k - 2 * D)];
        else {
            int d = k - 2 * D - FT;
            float a = 0.f;
            for (int j = 0; j < len; ++j) a += p[j] * emb[(st + j) * D + d];
            val = a;
        }
        temb[(size_t)t * SD + k] = val;
    }
}

// ---------------- generic fp32 tiled GEMM: C[M,N] = A[M,K(lda)] @ B[K,N(ldb)] ----------------
__global__ __launch_bounds__(256) void k_gemm_f32(const float* __restrict__ A,
                                                  const float* __restrict__ B,
                                                  float* __restrict__ C,
                                                  int M, int N, int K,
                                                  int lda, int ldb, int ldc) {
    int m0 = blockIdx.x * 64, n0 = blockIdx.y * 64;
    __shared__ float As[32][65], Bs[32][65];
    int tid = threadIdx.x, tx = tid & 15, ty = tid >> 4;
    float acc[4][4] = {};
    for (int k0 = 0; k0 < K; k0 += 32) {
        for (int i = 0; i < 8; ++i) {
            int lid = tid + i * 256;
            int r = lid >> 5, kk = lid & 31;
            int m = m0 + r, k = k0 + kk;
            As[kk][r] = (m < M && k < K) ? A[(size_t)m * lda + k] : 0.f;
        }
        for (int i = 0; i < 8; ++i) {
            int lid = tid + i * 256;
            int r = lid >> 6, nn = lid & 63;
            int k = k0 + r, n = n0 + nn;
            Bs[r][nn] = (k < K && n < N) ? B[(size_t)k * ldb + n] : 0.f;
        }
        __syncthreads();
        for (int kk = 0; kk < 32; ++kk) {
            float a[4], b[4];
            for (int i = 0; i < 4; ++i) a[i] = As[kk][ty * 4 + i];
            for (int j = 0; j < 4; ++j) b[j] = Bs[kk][tx * 4 + j];
            for (int i = 0; i < 4; ++i)
                for (int j = 0; j < 4; ++j) acc[i][j] += a[i] * b[j];
        }
        __syncthreads();
    }
    for (int i = 0; i < 4; ++i)
        for (int j = 0; j < 4; ++j) {
            int m = m0 + ty * 4 + i, n = n0 + tx * 4 + j;
            if (m < M && n < N) C[(size_t)m * ldc + n] = acc[i][j];
        }
}

// coarse[x][y] = biaff + ment sums + mask + dist prior
__global__ __launch_bounds__(256) void k_biaff2(const float* tmp, const float* temb,
                                                const float* tme, const float* dpr,
                                                float* coarse) {
    int m0 = blockIdx.x * 64, n0 = blockIdx.y * 64;
    __shared__ float As[32][65], Bs[32][65];
    int tid = threadIdx.x, tx = tid & 15, ty = tid >> 4;
    float acc[4][4] = {};
    for (int k0 = 0; k0 < SD; k0 += 32) {
        for (int i = 0; i < 8; ++i) {
            int lid = tid + i * 256;
            int r = lid >> 5, kk = lid & 31;
            int m = m0 + r, k = k0 + kk;
            As[kk][r] = (m < TOPN && k < SD) ? tmp[(size_t)m * (SD + 1) + k] : 0.f;
        }
        for (int i = 0; i < 8; ++i) {
            int lid = tid + i * 256;
            int y = lid >> 5, kk = lid & 31;
            int n = n0 + y, k = k0 + kk;
            Bs[kk][y] = (n < TOPN && k < SD) ? temb[(size_t)n * SD + k] : 0.f;
        }
        __syncthreads();
        for (int kk = 0; kk < 32; ++kk) {
            float a[4], b[4];
            for (int i = 0; i < 4; ++i) a[i] = As[kk][ty * 4 + i];
            for (int j = 0; j < 4; ++j) b[j] = Bs[kk][tx * 4 + j];
            for (int i = 0; i < 4; ++i)
                for (int j = 0; j < 4; ++j) acc[i][j] += a[i] * b[j];
        }
        __syncthreads();
    }
    for (int i = 0; i < 4; ++i)
        for (int j = 0; j < 4; ++j) {
            int x = m0 + ty * 4 + i, y = n0 + tx * 4 + j;
            if (x < TOPN && y < TOPN) {
                float val = acc[i][j] + tmp[(size_t)x * (SD + 1) + SD] + tme[x] + tme[y];
                int off = x - y;
                val += (off >= 1) ? 0.f : NEGF;
                val += dpr[bucket_dist(max(off, 0))];
                coarse[(size_t)x * TOPN + y] = val;
            }
        }
}

// per-row top-50 (value desc, index asc tie-break)
__global__ __launch_bounds__(256) void k_topant(const float* coarse, int* anti,
                                                float* antc, float* out_ai) {
    int x = blockIdx.x;
    int tid = threadIdx.x;
    __shared__ float vals[512];
    __shared__ unsigned long long red[256];
    vals[tid] = (tid < TOPN) ? coarse[(size_t)x * TOPN + tid] : -INFINITY;
    vals[tid + 256] = (tid + 256 < TOPN) ? coarse[(size_t)x * TOPN + tid + 256] : -INFINITY;
    __syncthreads();
    for (int j = 0; j < KA; ++j) {
        unsigned long long best = 0ull;
        for (int h = 0; h < 2; ++h) {
            int y = tid + h * 256;
            unsigned long long p = ((unsigned long long)f2sort(vals[y]) << 32)
                                 | (unsigned long long)(0xFFFFFFFFu - (unsigned int)y);
            if (p > best) best = p;
        }
        red[tid] = best; __syncthreads();
        for (int s = 128; s; s >>= 1) {
            if (tid < s) { if (red[tid + s] > red[tid]) red[tid] = red[tid + s]; }
            __syncthreads();
        }
        if (tid == 0) {
            unsigned long long r = red[0];
            int y = (int)(0xFFFFFFFFu - (unsigned int)(r & 0xFFFFFFFFu));
            anti[x * KA + j] = y;
            antc[x * KA + j] = vals[y];
            out_ai[x * KA + j] = (float)y;
            vals[y] = -INFINITY;
        }
        __syncthreads();
    }
}

// ---------------- bf16 MFMA GEMM (128x128 tile, 4 waves, reg-prefetch staging) ----------------
// MODE 0 (ST):   A = tembh rows [512][KP], B = w1t_st [2048][KP]; writes Hst[512][2048] f32.
// MODE 1 (PROD): A row m = tembh[t] * tembh[a] (t=m/KA, a=anti[m]); B = w1t_p [1024][KP];
//                fused epilogue: slow[m] += sum_n relu(acc + Hsrc + Htgt + P-lookups) * w2[n].
template<int MODE>
__global__ __launch_bounds__(256) void k_mm(
    const unsigned short* __restrict__ tembh, const unsigned short* __restrict__ w1t,
    const int* __restrict__ anti, const int* __restrict__ tstv,
    const int* __restrict__ spk, const int* __restrict__ seg,
    const float* __restrict__ Hst, const float* __restrict__ Pall,
    const float* __restrict__ w2, float* __restrict__ outp) {
    __shared__ unsigned short As[128 * 40];
    __shared__ unsigned short Bs[128 * 40];
    const int tid = threadIdx.x;
    const int m0 = blockIdx.x * 128, n0 = blockIdx.y * 128;
    const int l = tid & 63, wv = tid >> 6, wr = wv >> 1, wc = wv & 1;
    const int r = tid >> 1, h = tid & 1;

    const unsigned short *pa0, *pa1;
    bool za = false;
    if (MODE == 0) {
        pa0 = tembh + (size_t)(m0 + r) * KP + h * 16;
        pa1 = pa0;
    } else {
        int m = m0 + r;
        if (m < MP) {
            int t = m / KA; int a = anti[m];
            pa0 = tembh + (size_t)t * KP + h * 16;
            pa1 = tembh + (size_t)a * KP + h * 16;
        } else { za = true; pa0 = tembh; pa1 = tembh; }
    }
    const unsigned short* pb = w1t + (size_t)(n0 + r) * KP + h * 16;
    unsigned short* awr = As + r * 40 + h * 16;
    unsigned short* bwr = Bs + r * 40 + h * 16;

    short8 ra0, ra1, rb0, rb1, rc0, rc1;
    ra0 = *(const short8*)(pa0); ra1 = *(const short8*)(pa0 + 8);
    if (MODE == 1) { rb0 = *(const short8*)(pa1); rb1 = *(const short8*)(pa1 + 8); }
    rc0 = *(const short8*)(pb);  rc1 = *(const short8*)(pb + 8);

    f32x4 acc[4][4];
    #pragma unroll
    for (int i = 0; i < 4; ++i)
        #pragma unroll
        for (int j = 0; j < 4; ++j) acc[i][j] = (f32x4){0.f, 0.f, 0.f, 0.f};

    for (int kt = 0; kt < NKT; ++kt) {
        __syncthreads();
        short8 wa0, wa1;
        if (MODE == 0) { wa0 = ra0; wa1 = ra1; }
        else {
            #pragma unroll
            for (int e = 0; e < 8; ++e) {
                float x0 = bf2f((unsigned short)ra0[e]) * bf2f((unsigned short)rb0[e]);
                float x1 = bf2f((unsigned short)ra1[e]) * bf2f((unsigned short)rb1[e]);
                wa0[e] = za ? (short)0 : (short)f2bf(x0);
                wa1[e] = za ? (short)0 : (short)f2bf(x1);
            }
        }
        *(short8*)(awr) = wa0; *(short8*)(awr + 8) = wa1;
        *(short8*)(bwr) = rc0; *(short8*)(bwr + 8) = rc1;
        __syncthreads();
        if (kt + 1 < NKT) {
            int ko = (kt + 1) * 32;
            ra0 = *(const short8*)(pa0 + ko); ra1 = *(const short8*)(pa0 + ko + 8);
            if (MODE == 1) { rb0 = *(const short8*)(pa1 + ko); rb1 = *(const short8*)(pa1 + ko + 8); }
            rc0 = *(const short8*)(pb + ko);  rc1 = *(const short8*)(pb + ko + 8);
        }
        short8 af[4], bfr[4];
        #pragma unroll
        for (int mf = 0; mf < 4; ++mf)
            af[mf] = *(const short8*)(As + (wr * 64 + mf * 16 + (l & 15)) * 40 + (l >> 4) * 8);
        #pragma unroll
        for (int nf = 0; nf < 4; ++nf)
            bfr[nf] = *(const short8*)(Bs + (wc * 64 + nf * 16 + (l & 15)) * 40 + (l >> 4) * 8);
        #pragma unroll
        for (int mf = 0; mf < 4; ++mf)
            #pragma unroll
            for (int nf = 0; nf < 4; ++nf)
                acc[mf][nf] = __builtin_amdgcn_mfma_f32_16x16x32_bf16(af[mf], bfr[nf], acc[mf][nf], 0, 0, 0);
    }

    if (MODE == 0) {
        #pragma unroll
        for (int mf = 0; mf < 4; ++mf)
            #pragma unroll
            for (int nf = 0; nf < 4; ++nf)
                #pragma unroll
                for (int rg = 0; rg < 4; ++rg) {
                    int m = m0 + wr * 64 + mf * 16 + (l >> 4) * 4 + rg;
                    int n = n0 + wc * 64 + nf * 16 + (l & 15);
                    outp[(size_t)m * 2048 + n] = acc[mf][nf][rg];
                }
    } else {
        #pragma unroll
        for (int mf = 0; mf < 4; ++mf) {
            #pragma unroll
            for (int rg = 0; rg < 4; ++rg) {
                int m = m0 + wr * 64 + mf * 16 + (l >> 4) * 4 + rg;
                float ps = 0.f;
                if (m < MP) {
                    int t = m / KA; int a = anti[m];
                    int u1 = tstv[t], u2 = tstv[a];
                    const float* rs = Hst + (size_t)t * 2048;
                    const float* rt = Hst + (size_t)a * 2048 + 1024;
                    const float* q1 = Pall + ((spk[u1] == spk[u2]) ? 1 : 0) * 1024;
                    const float* q2 = Pall + 2 * 1024;
                    int sdv = seg[u1] - seg[u2]; sdv = min(max(sdv, 0), 10);
                    const float* q3 = Pall + (3 + sdv) * 1024;
                    const float* q4 = Pall + (14 + bucket_dist(max(t - a, 0))) * 1024;
                    #pragma unroll
                    for (int nf = 0; nf < 4; ++nf) {
                        int n = n0 + wc * 64 + nf * 16 + (l & 15);
                        if (n < FF) {
                            float v = acc[mf][nf][rg] + rs[n] + rt[n] + q1[n] + q2[n] + q3[n] + q4[n];
                            ps += fmaxf(v, 0.f) * w2[n];
                        }
                    }
                }
                ps += __shfl_xor(ps, 1); ps += __shfl_xor(ps, 2);
                ps += __shfl_xor(ps, 4); ps += __shfl_xor(ps, 8);
                if ((l & 15) == 0 && m < MP) atomicAdd(&outp[m], ps);
            }
        }
    }
}

__global__ void k_final(const int* anti, const float* slow, const float* antc, float* out_f) {
    int t = blockIdx.x, j = threadIdx.x;
    if (j < KA) {
        int a = anti[t * KA + j];
        float sc = (a < t) ? (slow[t * KA + j] + antc[t * KA + j]) : NEGF;
        out_f[t * (KA + 1) + 1 + j] = sc;
    }
    if (j == KA) out_f[t * (KA + 1)] = 0.f;
}

extern "C" void kernel_launch(void* const* d_in, const int* in_sizes, int n_in,
                              void* d_out, int out_size, void* d_ws, size_t ws_size,
                              hipStream_t stream) {
    const float* token_embs = (const float*)d_in[0];
    const int*   speaker    = (const int*)d_in[1];
    const int*   sentmap    = (const int*)d_in[2];
    const int*   segids     = (const int*)d_in[3];
    const int*   genre      = (const int*)d_in[4];
    const float* e_width    = (const float*)d_in[5];
    const float* e_width_pr = (const float*)d_in[6];
    const float* w_matt     = (const float*)d_in[7];
    const float* b_matt     = (const float*)d_in[8];
    const float* w_s1       = (const float*)d_in[9];
    const float* b_s1       = (const float*)d_in[10];
    const float* w_s2       = (const float*)d_in[11];
    const float* b_s2       = (const float*)d_in[12];
    const float* w_w1       = (const float*)d_in[13];
    const float* b_w1       = (const float*)d_in[14];
    const float* w_w2       = (const float*)d_in[15];
    const float* b_w2       = (const float*)d_in[16];
    const float* w_bi       = (const float*)d_in[17];
    const float* e_adp      = (const float*)d_in[18];
    const float* w_ad       = (const float*)d_in[19];
    const float* b_ad       = (const float*)d_in[20];
    const float* e_same     = (const float*)d_in[21];
    const float* e_genre    = (const float*)d_in[22];
    const float* e_seg      = (const float*)d_in[23];
    const float* e_antd     = (const float*)d_in[24];
    const float* w_p1       = (const float*)d_in[25];
    const float* b_p1       = (const float*)d_in[26];
    const float* w_p2       = (const float*)d_in[27];
    const float* b_p2       = (const float*)d_in[28];

    float* F = (float*)d_ws;
    float* tokatt = F + O_TOKATT;
    float* wps    = F + O_WPS;
    float* dpr    = F + O_DPR;
    float* ment   = F + O_MENT;
    int*   tidx   = (int*)(F + O_TIDX);
    int*   tst    = (int*)(F + O_TST);
    int*   ten    = (int*)(F + O_TEN);
    float* tme    = F + O_TME;
    float* temb   = F + O_TEMB;
    float* tmpb   = F + O_TMPB;
    float* coarse = F + O_COARSE;
    int*   anti   = (int*)(F + O_ANTI);
    float* antc   = F + O_ANTC;
    float* slow   = F + O_SLOW;
    float* E      = F + O_E;
    float* e2w    = F + O_E2W;
    float* pall   = F + O_PALL;
    float* hst    = F + O_HST;
    unsigned short* tembh = (unsigned short*)(F + O_TEMBH);
    unsigned short* w1st  = (unsigned short*)(F + O_W1ST);
    unsigned short* w1p   = (unsigned short*)(F + O_W1P);

    float* out    = (float*)d_out;
    float* out_s  = out;
    float* out_e  = out + TOPN;
    float* out_ai = out + 2 * TOPN;
    float* out_f  = out + 2 * TOPN + MP;

    // weight-only prep
    k_init<<<(MP + 255) / 256, 256, 0, stream>>>(b_p2, slow);
    k_cvt_w1<<<dim3(NKT, 64), 256, 0, stream>>>(w_p1, w1st, 0);
    k_cvt_w1<<<dim3(NKT, 32), 256, 0, stream>>>(w_p1, w1p, 1);
    k_prep_pall<<<(24 * 1024 + 255) / 256, 256, 0, stream>>>(w_p1, b_p1, genre,
                                                             e_same, e_genre, e_seg, e_antd, pall);
    k_tokatt<<<NT / 4, 256, 0, stream>>>(token_embs, w_matt, b_matt, tokatt);
    k_widthps<<<SW, 256, 0, stream>>>(e_width_pr, w_w1, b_w1, w_w2, b_w2, wps);
    k_distpr<<<1, 64, 0, stream>>>(e_adp, w_ad, b_ad, dpr);

    // E = emb @ W1-slices (start|end|head), fp32 (feeds selection)
    {
        dim3 g(NT / 64, (FF + 63) / 64);
        k_gemm_f32<<<g, 256, 0, stream>>>(token_embs, w_s1,               E,        NT, FF, D, D, FF, 3072);
        k_gemm_f32<<<g, 256, 0, stream>>>(token_embs, w_s1 + D * FF,      E + 1024, NT, FF, D, D, FF, 3072);
        k_gemm_f32<<<g, 256, 0, stream>>>(token_embs, w_s1 + (2*D+FT)*FF, E + 2048, NT, FF, D, D, FF, 3072);
    }
    k_e2w<<<(30 * 1024 + 255) / 256, 256, 0, stream>>>(e_width, w_s1, e2w);

    k_ment<<<NT, 256, 0, stream>>>(E, e2w, tokatt, sentmap, b_s1, w_s2, wps, b_s2, ment);
    k_topk<<<1, 1024, 0, stream>>>(ment, tidx);
    k_gather<<<TOPN, 256, 0, stream>>>(token_embs, e_width, tokatt, ment, tidx,
                                       tst, ten, tme, temb, out_s, out_e);
    k_cvt_temb<<<(512 * KP + 255) / 256, 256, 0, stream>>>(temb, tembh);

    // biaffine (fp32, feeds antecedent selection)
    {
        dim3 g((TOPN + 63) / 64, (SD + 1 + 63) / 64);
        k_gemm_f32<<<g, 256, 0, stream>>>(temb, w_bi, tmpb, TOPN, SD + 1, SD, SD, SD + 1, SD + 1);
    }
    {
        dim3 g((TOPN + 63) / 64, (TOPN + 63) / 64);
        k_biaff2<<<g, 256, 0, stream>>>(tmpb, temb, tme, dpr, coarse);
    }
    k_topant<<<TOPN, 256, 0, stream>>>(coarse, anti, antc, out_ai);

    // pair path (bf16 MFMA, output-3 only)
    k_mm<0><<<dim3(4, 16), 256, 0, stream>>>(tembh, w1st, anti, tst, speaker, segids,
                                             hst, pall, w_p2, hst);
    k_mm<1><<<dim3(160, 8), 256, 0, stream>>>(tembh, w1p, anti, tst, speaker, segids,
                                              hst, pall, w_p2, slow);
    k_final<<<TOPN, 64, 0, stream>>>(anti, slow, antc, out_f);
}

// Round 4
// 1100.246 us; speedup vs baseline: 15.0416x; 1.9196x over previous
//
#include <hip/hip_runtime.h>
#include <math.h>

#define NEGF (-1e9f)

constexpr int NT = 1024;             // tokens
constexpr int D  = 768;
constexpr int SW = 30;               // max span width
constexpr int NC = NT * SW;          // 30720 candidates
constexpr int FT = 20;
constexpr int FF = 1000;
constexpr int TOPN = 409;            // int(0.4*1024)
constexpr int KA = 50;
constexpr int SD = 2 * D + FT + D;   // 2324
constexpr int MP = TOPN * KA;        // 20450
constexpr int KP = 2336;             // SD padded to mult of 32
constexpr int NKT = KP / 32;         // 73

typedef short short8 __attribute__((ext_vector_type(8)));
typedef float f32x4 __attribute__((ext_vector_type(4)));

// ---- ws layout (float units), ~42 MB total ----
constexpr size_t al8(size_t x) { return (x + 7) & ~(size_t)7; }
constexpr size_t O_TOKATT = 0;                                     // 1024
constexpr size_t O_WPS    = al8(O_TOKATT + 1024);                  // 32
constexpr size_t O_DPR    = al8(O_WPS + 32);                       // 16
constexpr size_t O_MENT   = al8(O_DPR + 16);                       // NC
constexpr size_t O_TIDX   = al8(O_MENT + NC);                      // 512
constexpr size_t O_TST    = al8(O_TIDX + 512);
constexpr size_t O_TEN    = al8(O_TST + 512);
constexpr size_t O_TME    = al8(O_TEN + 512);
constexpr size_t O_TEMB   = al8(O_TME + 512);                      // 409*2324
constexpr size_t O_TMPB   = al8(O_TEMB + (size_t)TOPN * SD);       // 409*2325
constexpr size_t O_COARSE = al8(O_TMPB + (size_t)TOPN * (SD + 1)); // 409*409
constexpr size_t O_ANTI   = al8(O_COARSE + (size_t)TOPN * TOPN);   // 20480
constexpr size_t O_ANTC   = al8(O_ANTI + 20480);
constexpr size_t O_SLOW   = al8(O_ANTC + 20480);
constexpr size_t O_E      = al8(O_SLOW + 20480);                   // 1024*3072 (s|e|h)
constexpr size_t O_E2W    = al8(O_E + (size_t)NT * 3072);          // 30*1024
constexpr size_t O_PALL   = al8(O_E2W + 30 * 1024);                // 24*1024
constexpr size_t O_HST    = al8(O_PALL + 24 * 1024);               // 512*2048
constexpr size_t O_TEMBH  = al8(O_HST + (size_t)512 * 2048);       // 512*2336 bf16 -> /2 floats
constexpr size_t O_W1ST   = al8(O_TEMBH + (size_t)512 * KP / 2);   // 2048*2336 bf16
constexpr size_t O_W1P    = al8(O_W1ST + (size_t)2048 * KP / 2);   // 1024*2336 bf16

__device__ __forceinline__ unsigned int f2sort(float f) {
    unsigned int u = __float_as_uint(f);
    return (u & 0x80000000u) ? ~u : (u | 0x80000000u);
}
__device__ __forceinline__ int bucket_dist(int d) {   // d >= 0
    if (d <= 4) return d;
    return min(34 - __clz(d), 9);                     // floor(log2(d)) + 3, clipped
}
__device__ __forceinline__ unsigned short f2bf(float f) {   // RNE f32 -> bf16
    unsigned u = __float_as_uint(f);
    unsigned r = (u + 0x7fffu + ((u >> 16) & 1u)) >> 16;
    return (unsigned short)r;
}
__device__ __forceinline__ float bf2f(unsigned short s) {
    return __uint_as_float(((unsigned)s) << 16);
}

// ---------------- small prep kernels ----------------
__global__ void k_init(const float* b_p2, float* slow) {
    int i = blockIdx.x * 256 + threadIdx.x;
    if (i < MP) slow[i] = b_p2[0];
}

__global__ void k_zero(float* p, int n) {
    int i = blockIdx.x * 256 + threadIdx.x;
    if (i < n) p[i] = 0.f;
}
__global__ void k_zero4(float* p, int n4) {   // n4 = n/4
    int i = blockIdx.x * 256 + threadIdx.x;
    if (i < n4) ((float4*)p)[i] = make_float4(0.f, 0.f, 0.f, 0.f);
}

__global__ void k_tokatt(const float* emb, const float* w, const float* b, float* out) {
    int wave = threadIdx.x >> 6, lane = threadIdx.x & 63;
    int tok = blockIdx.x * 4 + wave;
    float s = 0.f;
    for (int d = lane; d < D; d += 64) s += emb[tok * D + d] * w[d];
    for (int o = 32; o; o >>= 1) s += __shfl_down(s, o);
    if (lane == 0) out[tok] = s + b[0];
}

__global__ void k_widthps(const float* e, const float* w1, const float* b1,
                          const float* w2, const float* b2, float* out) {
    int wi = blockIdx.x;
    float acc = 0.f;
    for (int n = threadIdx.x; n < FF; n += 256) {
        float h = b1[n];
        for (int f = 0; f < FT; ++f) h += e[wi * FT + f] * w1[f * FF + n];
        acc += fmaxf(h, 0.f) * w2[n];
    }
    __shared__ float red[256];
    red[threadIdx.x] = acc; __syncthreads();
    for (int s = 128; s; s >>= 1) {
        if (threadIdx.x < s) red[threadIdx.x] += red[threadIdx.x + s];
        __syncthreads();
    }
    if (threadIdx.x == 0) out[wi] = red[0] + b2[0];
}

__global__ void k_distpr(const float* e, const float* w, const float* b, float* out) {
    int d = threadIdx.x;
    if (d < 10) {
        float s = b[0];
        for (int f = 0; f < FT; ++f) s += e[d * FT + f] * w[f];
        out[d] = s;
    }
}

// E2W[wd][n] = sum_f e_width[wd][f] * w_s1[(1536+f)][n]
__global__ void k_e2w(const float* ew, const float* w1, float* e2w) {
    int idx = blockIdx.x * 256 + threadIdx.x;
    if (idx >= 30 * 1024) return;
    int wd = idx >> 10, n = idx & 1023;
    float s = 0.f;
    if (n < FF) for (int f = 0; f < FT; ++f) s += ew[wd * FT + f] * w1[(2 * D + f) * FF + n];
    e2w[idx] = s;
}

// Pall rows: 0-1 same-speaker, 2 genre + b_p1, 3..13 seg-dist, 14..23 ant-dist
__global__ void k_prep_pall(const float* w1, const float* b1, const int* genre,
                            const float* e_same, const float* e_genre,
                            const float* e_seg, const float* e_antd, float* pall) {
    int idx = blockIdx.x * 256 + threadIdx.x;
    if (idx >= 24 * 1024) return;
    int r = idx >> 10, n = idx & 1023;
    float s = 0.f;
    if (n < FF) {
        const float* tab; int foff;
        if (r < 2)       { tab = e_same + r * FT;          foff = 0; }
        else if (r == 2) { tab = e_genre + genre[0] * FT;  foff = FT; s = b1[n]; }
        else if (r < 14) { tab = e_seg + (r - 3) * FT;     foff = 2 * FT; }
        else             { tab = e_antd + (r - 14) * FT;   foff = 3 * FT; }
        for (int f = 0; f < FT; ++f) s += tab[f] * w1[(size_t)(3 * SD + foff + f) * FF + n];
    }
    pall[idx] = s;
}

// temb (fp32, 409xSD) -> tembh (bf16, 512xKP, zero-padded)
__global__ void k_cvt_temb(const float* temb, unsigned short* tembh) {
    int idx = blockIdx.x * 256 + threadIdx.x;
    if (idx >= 512 * KP) return;
    int t = idx / KP, k = idx % KP;
    float v = (t < TOPN && k < SD) ? temb[(size_t)t * SD + k] : 0.f;
    tembh[idx] = f2bf(v);
}

// w_p1 slices -> transposed bf16 [RN][KP]. mode 0: RN=2048 (src|tgt halves); mode 1: RN=1024 (prod)
__global__ void k_cvt_w1(const float* w1, unsigned short* dst, int mode) {
    __shared__ float tile[32][33];
    int kp0 = blockIdx.x * 32;
    int r0  = blockIdx.y * 32;
    int tx = threadIdx.x & 31, ty = threadIdx.x >> 5;
    for (int i = 0; i < 4; ++i) {
        int r = r0 + tx, kp = kp0 + ty + i * 8;
        int c, ro;
        if (mode == 0) { c = r & 1023; ro = (r >> 10) * SD; }
        else           { c = r;        ro = 2 * SD; }
        float v = (c < FF && kp < SD) ? w1[(size_t)(ro + kp) * FF + c] : 0.f;
        tile[ty + i * 8][tx] = v;
    }
    __syncthreads();
    for (int i = 0; i < 4; ++i) {
        int r = r0 + ty + i * 8, kp = kp0 + tx;
        dst[(size_t)r * KP + kp] = f2bf(tile[tx][ty + i * 8]);
    }
}

// ---------------- mention scores: per-start block, incremental attention ----------------
__global__ __launch_bounds__(256) void k_ment(
    const float* __restrict__ E, const float* __restrict__ e2w,
    const float* __restrict__ tokatt, const int* __restrict__ sentmap,
    const float* __restrict__ b1, const float* __restrict__ w2,
    const float* __restrict__ wps, const float* __restrict__ b_s2, float* ment) {
    int st = blockIdx.x;
    __shared__ float earr[32];
    __shared__ int vmask[32];
    __shared__ float swred[4][32];
    int tid = threadIdx.x;
    if (tid < SW) {
        int en = st + tid;
        bool ok = en < NT;
        earr[tid] = ok ? expf(tokatt[en]) : 0.f;
        vmask[tid] = ok && (sentmap[st] == sentmap[en]);
    }
    __syncthreads();
    int n4 = tid * 4;
    bool act = n4 < FF;
    float4 Es = {0,0,0,0}, B1 = {0,0,0,0}, W2 = {0,0,0,0};
    if (act) {
        Es = *(const float4*)(E + (size_t)st * 3072 + n4);
        B1 = *(const float4*)(b1 + n4);
        W2 = *(const float4*)(w2 + n4);
    }
    float Ux = 0, Uy = 0, Uz = 0, Uw = 0, S = 0.f;
    float part[SW];
    #pragma unroll
    for (int wd = 0; wd < SW; ++wd) {
        int en = st + wd;
        float p = 0.f;
        if (en < NT) {
            float e = earr[wd]; S += e;
            if (act) {
                float4 Eh = *(const float4*)(E + (size_t)en * 3072 + 2048 + n4);
                Ux += e * Eh.x; Uy += e * Eh.y; Uz += e * Eh.z; Uw += e * Eh.w;
                if (vmask[wd]) {
                    float inv = 1.f / S;
                    float4 Ee = *(const float4*)(E + (size_t)en * 3072 + 1024 + n4);
                    float4 Ww = *(const float4*)(e2w + wd * 1024 + n4);
                    float vx = Es.x + Ee.x + Ww.x + B1.x + Ux * inv;
                    float vy = Es.y + Ee.y + Ww.y + B1.y + Uy * inv;
                    float vz = Es.z + Ee.z + Ww.z + B1.z + Uz * inv;
                    float vw = Es.w + Ee.w + Ww.w + B1.w + Uw * inv;
                    p = fmaxf(vx, 0.f) * W2.x + fmaxf(vy, 0.f) * W2.y
                      + fmaxf(vz, 0.f) * W2.z + fmaxf(vw, 0.f) * W2.w;
                }
            }
        }
        part[wd] = p;
    }
    int lane = tid & 63, wv = tid >> 6;
    #pragma unroll
    for (int wd = 0; wd < SW; ++wd) {
        float r = part[wd];
        r += __shfl_xor(r, 1);  r += __shfl_xor(r, 2);  r += __shfl_xor(r, 4);
        r += __shfl_xor(r, 8);  r += __shfl_xor(r, 16); r += __shfl_xor(r, 32);
        if (lane == 0) swred[wv][wd] = r;
    }
    __syncthreads();
    if (tid < SW) {
        float tot = swred[0][tid] + swred[1][tid] + swred[2][tid] + swred[3][tid];
        ment[st * SW + tid] = vmask[tid] ? (tot + wps[tid] + b_s2[0]) : NEGF;
    }
}

// ---------------- top-409 selection (single block) ----------------
__global__ __launch_bounds__(1024) void k_topk(const float* ment, int* topidx) {
    __shared__ unsigned int hist[256];
    __shared__ unsigned int sc[1024];
    __shared__ unsigned int sh_prefix, sh_needed, sh_run, sh_base2, sh_rune;
    int tid = threadIdx.x;
    if (tid == 0) { sh_prefix = 0; sh_needed = TOPN; }
    for (int r = 3; r >= 0; --r) {
        if (tid < 256) hist[tid] = 0;
        __syncthreads();
        unsigned int pref = sh_prefix;
        for (int c = tid; c < NC; c += 1024) {
            unsigned int u = f2sort(ment[c]);
            bool match = (r == 3) || ((u >> ((r + 1) * 8)) == pref);
            if (match) atomicAdd(&hist[(u >> (r * 8)) & 255u], 1u);
        }
        __syncthreads();
        if (tid == 0) {
            unsigned int need = sh_needed, cum = 0; int sel = 0;
            for (int b = 255; b >= 0; --b) {
                if (cum + hist[b] >= need) { sel = b; sh_needed = need - cum; break; }
                cum += hist[b];
            }
            sh_prefix = (sh_prefix << 8) | (unsigned int)sel;
        }
        __syncthreads();
    }
    unsigned int kth = sh_prefix;
    unsigned int quota = sh_needed;
    if (tid == 0) sh_run = 0;
    __syncthreads();
    for (int base = 0; base < NC; base += 1024) {
        int c = base + tid;
        unsigned int u = f2sort(ment[c]);
        unsigned int flag = (u > kth) ? 1u : 0u;
        sc[tid] = flag; __syncthreads();
        for (int off = 1; off < 1024; off <<= 1) {
            unsigned int v = (tid >= off) ? sc[tid - off] : 0u;
            __syncthreads();
            sc[tid] += v;
            __syncthreads();
        }
        if (flag) topidx[sh_run + sc[tid] - 1] = c;
        unsigned int tot = sc[1023];
        __syncthreads();
        if (tid == 0) sh_run += tot;
        __syncthreads();
    }
    if (tid == 0) { sh_base2 = sh_run; sh_rune = 0; }
    __syncthreads();
    for (int base = 0; base < NC; base += 1024) {
        int c = base + tid;
        unsigned int u = f2sort(ment[c]);
        unsigned int flag = (u == kth) ? 1u : 0u;
        sc[tid] = flag; __syncthreads();
        for (int off = 1; off < 1024; off <<= 1) {
            unsigned int v = (tid >= off) ? sc[tid - off] : 0u;
            __syncthreads();
            sc[tid] += v;
            __syncthreads();
        }
        if (flag && (sh_rune + sc[tid] - 1) < quota)
            topidx[sh_base2 + sh_rune + sc[tid] - 1] = c;
        unsigned int tot = sc[1023];
        __syncthreads();
        if (tid == 0) sh_rune += tot;
        __syncthreads();
    }
    __shared__ int arr[512];
    if (tid < 512) arr[tid] = (tid < TOPN) ? topidx[tid] : 0x7fffffff;
    __syncthreads();
    for (int k = 2; k <= 512; k <<= 1) {
        for (int j = k >> 1; j > 0; j >>= 1) {
            if (tid < 512) {
                int i = tid, p = i ^ j;
                if (p > i) {
                    bool asc = ((i & k) == 0);
                    int a = arr[i], b = arr[p];
                    if ((a > b) == asc) { arr[i] = b; arr[p] = a; }
                }
            }
            __syncthreads();
        }
    }
    if (tid < TOPN) topidx[tid] = arr[tid];
}

// gather top spans; computes head-attn emb on the fly
__global__ void k_gather(const float* emb, const float* wemb, const float* tokatt,
                         const float* ment, const int* topidx,
                         int* tst, int* ten, float* tme, float* temb,
                         float* out_s, float* out_e) {
    int t = blockIdx.x;
    int c = topidx[t];
    int st = c / SW, wd = c % SW;
    int en = min(st + wd, NT - 1);
    int len = en - st + 1;
    __shared__ float p[32];
    if (threadIdx.x == 0) {
        float m = -1e30f;
        for (int j = 0; j < len; ++j) m = fmaxf(m, tokatt[st + j]);
        float s = 0.f;
        for (int j = 0; j < len; ++j) { p[j] = expf(tokatt[st + j] - m); s += p[j]; }
        float inv = 1.f / s;
        for (int j = 0; j < len; ++j) p[j] *= inv;
        tst[t] = st; ten[t] = en; tme[t] = ment[c];
        out_s[t] = (float)st; out_e[t] = (float)en;
    }
    __syncthreads();
    for (int k = threadIdx.x; k < SD; k += 256) {
        float val;
        if (k < D) val = emb[st * D + k];
        else if (k < 2 * D) val = emb[en * D + (k - D)];
        else if (k < 2 * D + FT) val = wemb[wd * FT + (k - 2 * D)];
        else {
            int d = k - 2 * D - FT;
            float a = 0.f;
            for (int j = 0; j < len; ++j) a += p[j] * emb[(st + j) * D + d];
            val = a;
        }
        temb[(size_t)t * SD + k] = val;
    }
}

// ---------------- fp32 split-K GEMM: C[M,N] += A[M,K] @ B ----------------
// BT=0: B is [K][N] (ldb = row stride). BT=1: B is [N][K] (ldb = row stride).
// C must be pre-initialized; epilogue is atomicAdd (split-K over blockIdx.z).
template<int BT>
__global__ __launch_bounds__(256) void k_sgemm(
    const float* __restrict__ A, const float* __restrict__ B, float* __restrict__ C,
    int M, int N, int K, int lda, int ldb, int ldc, int kch) {
    int m0 = blockIdx.x * 64, n0 = blockIdx.y * 64;
    int kbeg = blockIdx.z * kch;
    int kend = min(K, kbeg + kch);
    __shared__ float As[32][68], Bs[32][68];
    int tid = threadIdx.x, tx = tid & 15, ty = tid >> 4;
    float acc[4][4] = {};
    float ra[8], rb[8];

    auto loadA = [&](int k0) {
        #pragma unroll
        for (int i = 0; i < 8; ++i) {
            int lid = tid + i * 256;
            int rr = lid >> 5, kk = lid & 31;
            int m = m0 + rr, k = k0 + kk;
            ra[i] = (m < M && k < kend) ? A[(size_t)m * lda + k] : 0.f;
        }
    };
    auto loadB = [&](int k0) {
        #pragma unroll
        for (int i = 0; i < 8; ++i) {
            int lid = tid + i * 256;
            if (BT) {
                int y = lid >> 5, kk = lid & 31;
                int n = n0 + y, k = k0 + kk;
                rb[i] = (n < N && k < kend) ? B[(size_t)n * ldb + k] : 0.f;
            } else {
                int rr = lid >> 6, nn = lid & 63;
                int k = k0 + rr, n = n0 + nn;
                rb[i] = (k < kend && n < N) ? B[(size_t)k * ldb + n] : 0.f;
            }
        }
    };

    loadA(kbeg); loadB(kbeg);
    for (int k0 = kbeg; k0 < kend; k0 += 32) {
        __syncthreads();   // previous compute done before overwriting LDS
        float sa[8], sb[8];
        #pragma unroll
        for (int i = 0; i < 8; ++i) { sa[i] = ra[i]; sb[i] = rb[i]; }
        #pragma unroll
        for (int i = 0; i < 8; ++i) {
            int lid = tid + i * 256;
            As[lid & 31][lid >> 5] = sa[i];
            if (BT) Bs[lid & 31][lid >> 5] = sb[i];
            else    Bs[lid >> 6][lid & 63] = sb[i];
        }
        __syncthreads();
        if (k0 + 32 < kend) { loadA(k0 + 32); loadB(k0 + 32); }
        #pragma unroll
        for (int kk = 0; kk < 32; ++kk) {
            float4 a = *(const float4*)&As[kk][ty * 4];
            float4 b = *(const float4*)&Bs[kk][tx * 4];
            acc[0][0] += a.x * b.x; acc[0][1] += a.x * b.y; acc[0][2] += a.x * b.z; acc[0][3] += a.x * b.w;
            acc[1][0] += a.y * b.x; acc[1][1] += a.y * b.y; acc[1][2] += a.y * b.z; acc[1][3] += a.y * b.w;
            acc[2][0] += a.z * b.x; acc[2][1] += a.z * b.y; acc[2][2] += a.z * b.z; acc[2][3] += a.z * b.w;
            acc[3][0] += a.w * b.x; acc[3][1] += a.w * b.y; acc[3][2] += a.w * b.z; acc[3][3] += a.w * b.w;
        }
    }
    #pragma unroll
    for (int i = 0; i < 4; ++i)
        #pragma unroll
        for (int j = 0; j < 4; ++j) {
            int m = m0 + ty * 4 + i, n = n0 + tx * 4 + j;
            if (m < M && n < N) atomicAdd(&C[(size_t)m * ldc + n], acc[i][j]);
        }
}

// coarse base: bias col + ment sums + mask + dist prior (split-K GEMM adds the dot product)
__global__ void k_initco(const float* tmpb, const float* tme, const float* dpr, float* coarse) {
    int idx = blockIdx.x * 256 + threadIdx.x;
    if (idx >= TOPN * TOPN) return;
    int x = idx / TOPN, y = idx - x * TOPN;
    int off = x - y;
    coarse[idx] = tmpb[(size_t)x * (SD + 1) + SD] + tme[x] + tme[y]
                + ((off >= 1) ? 0.f : NEGF) + dpr[bucket_dist(max(off, 0))];
}

// per-row top-50 (value desc, index asc tie-break)
__global__ __launch_bounds__(256) void k_topant(const float* coarse, int* anti,
                                                float* antc, float* out_ai) {
    int x = blockIdx.x;
    int tid = threadIdx.x;
    __shared__ float vals[512];
    __shared__ unsigned long long red[256];
    vals[tid] = (tid < TOPN) ? coarse[(size_t)x * TOPN + tid] : -INFINITY;
    vals[tid + 256] = (tid + 256 < TOPN) ? coarse[(size_t)x * TOPN + tid + 256] : -INFINITY;
    __syncthreads();
    for (int j = 0; j < KA; ++j) {
        unsigned long long best = 0ull;
        for (int h = 0; h < 2; ++h) {
            int y = tid + h * 256;
            unsigned long long p = ((unsigned long long)f2sort(vals[y]) << 32)
                                 | (unsigned long long)(0xFFFFFFFFu - (unsigned int)y);
            if (p > best) best = p;
        }
        red[tid] = best; __syncthreads();
        for (int s = 128; s; s >>= 1) {
            if (tid < s) { if (red[tid + s] > red[tid]) red[tid] = red[tid + s]; }
            __syncthreads();
        }
        if (tid == 0) {
            unsigned long long r = red[0];
            int y = (int)(0xFFFFFFFFu - (unsigned int)(r & 0xFFFFFFFFu));
            anti[x * KA + j] = y;
            antc[x * KA + j] = vals[y];
            out_ai[x * KA + j] = (float)y;
            vals[y] = -INFINITY;
        }
        __syncthreads();
    }
}

// ---------------- bf16 MFMA GEMM (128x128 tile, 4 waves, reg-prefetch staging) ----------------
// MODE 0 (ST):   A = tembh rows [512][KP], B = w1t_st [2048][KP]; writes Hst[512][2048] f32.
// MODE 1 (PROD): A row m = tembh[t] * tembh[a] (t=m/KA, a=anti[m]); B = w1t_p [1024][KP];
//                fused epilogue: slow[m] += sum_n relu(acc + Hsrc + Htgt + P-lookups) * w2[n].
template<int MODE>
__global__ __launch_bounds__(256) void k_mm(
    const unsigned short* __restrict__ tembh, const unsigned short* __restrict__ w1t,
    const int* __restrict__ anti, const int* __restrict__ tstv,
    const int* __restrict__ spk, const int* __restrict__ seg,
    const float* __restrict__ Hst, const float* __restrict__ Pall,
    const float* __restrict__ w2, float* __restrict__ outp) {
    __shared__ unsigned short As[128 * 40];
    __shared__ unsigned short Bs[128 * 40];
    const int tid = threadIdx.x;
    const int m0 = blockIdx.x * 128, n0 = blockIdx.y * 128;
    const int l = tid & 63, wv = tid >> 6, wr = wv >> 1, wc = wv & 1;
    const int r = tid >> 1, h = tid & 1;

    const unsigned short *pa0, *pa1;
    bool za = false;
    if (MODE == 0) {
        pa0 = tembh + (size_t)(m0 + r) * KP + h * 16;
        pa1 = pa0;
    } else {
        int m = m0 + r;
        if (m < MP) {
            int t = m / KA; int a = anti[m];
            pa0 = tembh + (size_t)t * KP + h * 16;
            pa1 = tembh + (size_t)a * KP + h * 16;
        } else { za = true; pa0 = tembh; pa1 = tembh; }
    }
    const unsigned short* pb = w1t + (size_t)(n0 + r) * KP + h * 16;
    unsigned short* awr = As + r * 40 + h * 16;
    unsigned short* bwr = Bs + r * 40 + h * 16;

    short8 ra0, ra1, rb0, rb1, rc0, rc1;
    ra0 = *(const short8*)(pa0); ra1 = *(const short8*)(pa0 + 8);
    if (MODE == 1) { rb0 = *(const short8*)(pa1); rb1 = *(const short8*)(pa1 + 8); }
    rc0 = *(const short8*)(pb);  rc1 = *(const short8*)(pb + 8);

    f32x4 acc[4][4];
    #pragma unroll
    for (int i = 0; i < 4; ++i)
        #pragma unroll
        for (int j = 0; j < 4; ++j) acc[i][j] = (f32x4){0.f, 0.f, 0.f, 0.f};

    for (int kt = 0; kt < NKT; ++kt) {
        __syncthreads();
        short8 wa0, wa1;
        if (MODE == 0) { wa0 = ra0; wa1 = ra1; }
        else {
            #pragma unroll
            for (int e = 0; e < 8; ++e) {
                float x0 = bf2f((unsigned short)ra0[e]) * bf2f((unsigned short)rb0[e]);
                float x1 = bf2f((unsigned short)ra1[e]) * bf2f((unsigned short)rb1[e]);
                wa0[e] = za ? (short)0 : (short)f2bf(x0);
                wa1[e] = za ? (short)0 : (short)f2bf(x1);
            }
        }
        *(short8*)(awr) = wa0; *(short8*)(awr + 8) = wa1;
        *(short8*)(bwr) = rc0; *(short8*)(bwr + 8) = rc1;
        __syncthreads();
        if (kt + 1 < NKT) {
            int ko = (kt + 1) * 32;
            ra0 = *(const short8*)(pa0 + ko); ra1 = *(const short8*)(pa0 + ko + 8);
            if (MODE == 1) { rb0 = *(const short8*)(pa1 + ko); rb1 = *(const short8*)(pa1 + ko + 8); }
            rc0 = *(const short8*)(pb + ko);  rc1 = *(const short8*)(pb + ko + 8);
        }
        short8 af[4], bfr[4];
        #pragma unroll
        for (int mf = 0; mf < 4; ++mf)
            af[mf] = *(const short8*)(As + (wr * 64 + mf * 16 + (l & 15)) * 40 + (l >> 4) * 8);
        #pragma unroll
        for (int nf = 0; nf < 4; ++nf)
            bfr[nf] = *(const short8*)(Bs + (wc * 64 + nf * 16 + (l & 15)) * 40 + (l >> 4) * 8);
        #pragma unroll
        for (int mf = 0; mf < 4; ++mf)
            #pragma unroll
            for (int nf = 0; nf < 4; ++nf)
                acc[mf][nf] = __builtin_amdgcn_mfma_f32_16x16x32_bf16(af[mf], bfr[nf], acc[mf][nf], 0, 0, 0);
    }

    if (MODE == 0) {
        #pragma unroll
        for (int mf = 0; mf < 4; ++mf)
            #pragma unroll
            for (int nf = 0; nf < 4; ++nf)
                #pragma unroll
                for (int rg = 0; rg < 4; ++rg) {
                    int m = m0 + wr * 64 + mf * 16 + (l >> 4) * 4 + rg;
                    int n = n0 + wc * 64 + nf * 16 + (l & 15);
                    outp[(size_t)m * 2048 + n] = acc[mf][nf][rg];
                }
    } else {
        #pragma unroll
        for (int mf = 0; mf < 4; ++mf) {
            #pragma unroll
            for (int rg = 0; rg < 4; ++rg) {
                int m = m0 + wr * 64 + mf * 16 + (l >> 4) * 4 + rg;
                float ps = 0.f;
                if (m < MP) {
                    int t = m / KA; int a = anti[m];
                    int u1 = tstv[t], u2 = tstv[a];
                    const float* rs = Hst + (size_t)t * 2048;
                    const float* rt = Hst + (size_t)a * 2048 + 1024;
                    const float* q1 = Pall + ((spk[u1] == spk[u2]) ? 1 : 0) * 1024;
                    const float* q2 = Pall + 2 * 1024;
                    int sdv = seg[u1] - seg[u2]; sdv = min(max(sdv, 0), 10);
                    const float* q3 = Pall + (3 + sdv) * 1024;
                    const float* q4 = Pall + (14 + bucket_dist(max(t - a, 0))) * 1024;
                    #pragma unroll
                    for (int nf = 0; nf < 4; ++nf) {
                        int n = n0 + wc * 64 + nf * 16 + (l & 15);
                        if (n < FF) {
                            float v = acc[mf][nf][rg] + rs[n] + rt[n] + q1[n] + q2[n] + q3[n] + q4[n];
                            ps += fmaxf(v, 0.f) * w2[n];
                        }
                    }
                }
                ps += __shfl_xor(ps, 1); ps += __shfl_xor(ps, 2);
                ps += __shfl_xor(ps, 4); ps += __shfl_xor(ps, 8);
                if ((l & 15) == 0 && m < MP) atomicAdd(&outp[m], ps);
            }
        }
    }
}

__global__ void k_final(const int* anti, const float* slow, const float* antc, float* out_f) {
    int t = blockIdx.x, j = threadIdx.x;
    if (j < KA) {
        int a = anti[t * KA + j];
        float sc = (a < t) ? (slow[t * KA + j] + antc[t * KA + j]) : NEGF;
        out_f[t * (KA + 1) + 1 + j] = sc;
    }
    if (j == KA) out_f[t * (KA + 1)] = 0.f;
}

extern "C" void kernel_launch(void* const* d_in, const int* in_sizes, int n_in,
                              void* d_out, int out_size, void* d_ws, size_t ws_size,
                              hipStream_t stream) {
    const float* token_embs = (const float*)d_in[0];
    const int*   speaker    = (const int*)d_in[1];
    const int*   sentmap    = (const int*)d_in[2];
    const int*   segids     = (const int*)d_in[3];
    const int*   genre      = (const int*)d_in[4];
    const float* e_width    = (const float*)d_in[5];
    const float* e_width_pr = (const float*)d_in[6];
    const float* w_matt     = (const float*)d_in[7];
    const float* b_matt     = (const float*)d_in[8];
    const float* w_s1       = (const float*)d_in[9];
    const float* b_s1       = (const float*)d_in[10];
    const float* w_s2       = (const float*)d_in[11];
    const float* b_s2       = (const float*)d_in[12];
    const float* w_w1       = (const float*)d_in[13];
    const float* b_w1       = (const float*)d_in[14];
    const float* w_w2       = (const float*)d_in[15];
    const float* b_w2       = (const float*)d_in[16];
    const float* w_bi       = (const float*)d_in[17];
    const float* e_adp      = (const float*)d_in[18];
    const float* w_ad       = (const float*)d_in[19];
    const float* b_ad       = (const float*)d_in[20];
    const float* e_same     = (const float*)d_in[21];
    const float* e_genre    = (const float*)d_in[22];
    const float* e_seg      = (const float*)d_in[23];
    const float* e_antd     = (const float*)d_in[24];
    const float* w_p1       = (const float*)d_in[25];
    const float* b_p1       = (const float*)d_in[26];
    const float* w_p2       = (const float*)d_in[27];
    const float* b_p2       = (const float*)d_in[28];

    float* F = (float*)d_ws;
    float* tokatt = F + O_TOKATT;
    float* wps    = F + O_WPS;
    float* dpr    = F + O_DPR;
    float* ment   = F + O_MENT;
    int*   tidx   = (int*)(F + O_TIDX);
    int*   tst    = (int*)(F + O_TST);
    int*   ten    = (int*)(F + O_TEN);
    float* tme    = F + O_TME;
    float* temb   = F + O_TEMB;
    float* tmpb   = F + O_TMPB;
    float* coarse = F + O_COARSE;
    int*   anti   = (int*)(F + O_ANTI);
    float* antc   = F + O_ANTC;
    float* slow   = F + O_SLOW;
    float* E      = F + O_E;
    float* e2w    = F + O_E2W;
    float* pall   = F + O_PALL;
    float* hst    = F + O_HST;
    unsigned short* tembh = (unsigned short*)(F + O_TEMBH);
    unsigned short* w1st  = (unsigned short*)(F + O_W1ST);
    unsigned short* w1p   = (unsigned short*)(F + O_W1P);

    float* out    = (float*)d_out;
    float* out_s  = out;
    float* out_e  = out + TOPN;
    float* out_ai = out + 2 * TOPN;
    float* out_f  = out + 2 * TOPN + MP;

    // weight-only prep
    k_init<<<(MP + 255) / 256, 256, 0, stream>>>(b_p2, slow);
    k_cvt_w1<<<dim3(NKT, 64), 256, 0, stream>>>(w_p1, w1st, 0);
    k_cvt_w1<<<dim3(NKT, 32), 256, 0, stream>>>(w_p1, w1p, 1);
    k_prep_pall<<<(24 * 1024 + 255) / 256, 256, 0, stream>>>(w_p1, b_p1, genre,
                                                             e_same, e_genre, e_seg, e_antd, pall);
    k_tokatt<<<NT / 4, 256, 0, stream>>>(token_embs, w_matt, b_matt, tokatt);
    k_widthps<<<SW, 256, 0, stream>>>(e_width_pr, w_w1, b_w1, w_w2, b_w2, wps);
    k_distpr<<<1, 64, 0, stream>>>(e_adp, w_ad, b_ad, dpr);

    // E = emb @ W1-slices (start|end|head), fp32 split-K (feeds selection)
    k_zero4<<<(NT * 3072 / 4 + 255) / 256, 256, 0, stream>>>(E, NT * 3072 / 4);
    {
        dim3 g(NT / 64, (FF + 63) / 64, 2);
        k_sgemm<0><<<g, 256, 0, stream>>>(token_embs, w_s1,                 E,        NT, FF, D, D, FF, 3072, 384);
        k_sgemm<0><<<g, 256, 0, stream>>>(token_embs, w_s1 + D * FF,        E + 1024, NT, FF, D, D, FF, 3072, 384);
        k_sgemm<0><<<g, 256, 0, stream>>>(token_embs, w_s1 + (2*D+FT) * FF, E + 2048, NT, FF, D, D, FF, 3072, 384);
    }
    k_e2w<<<(30 * 1024 + 255) / 256, 256, 0, stream>>>(e_width, w_s1, e2w);

    k_ment<<<NT, 256, 0, stream>>>(E, e2w, tokatt, sentmap, b_s1, w_s2, wps, b_s2, ment);
    k_topk<<<1, 1024, 0, stream>>>(ment, tidx);
    k_gather<<<TOPN, 256, 0, stream>>>(token_embs, e_width, tokatt, ment, tidx,
                                       tst, ten, tme, temb, out_s, out_e);
    k_cvt_temb<<<(512 * KP + 255) / 256, 256, 0, stream>>>(temb, tembh);

    // biaffine (fp32 split-K, feeds antecedent selection)
    k_zero<<<(TOPN * (SD + 1) + 255) / 256, 256, 0, stream>>>(tmpb, TOPN * (SD + 1));
    {
        dim3 g((TOPN + 63) / 64, (SD + 1 + 63) / 64, 4);
        k_sgemm<0><<<g, 256, 0, stream>>>(temb, w_bi, tmpb, TOPN, SD + 1, SD, SD, SD + 1, SD + 1, 608);
    }
    k_initco<<<(TOPN * TOPN + 255) / 256, 256, 0, stream>>>(tmpb, tme, dpr, coarse);
    {
        dim3 g((TOPN + 63) / 64, (TOPN + 63) / 64, 8);
        k_sgemm<1><<<g, 256, 0, stream>>>(tmpb, temb, coarse, TOPN, TOPN, SD, SD + 1, SD, TOPN, 320);
    }
    k_topant<<<TOPN, 256, 0, stream>>>(coarse, anti, antc, out_ai);

    // pair path (bf16 MFMA, output-3 only)
    k_mm<0><<<dim3(4, 16), 256, 0, stream>>>(tembh, w1st, anti, tst, speaker, segids,
                                             hst, pall, w_p2, hst);
    k_mm<1><<<dim3(160, 8), 256, 0, stream>>>(tembh, w1p, anti, tst, speaker, segids,
                                              hst, pall, w_p2, slow);
    k_final<<<TOPN, 64, 0, stream>>>(anti, slow, antc, out_f);
}

// Round 5
// 967.676 us; speedup vs baseline: 17.1023x; 1.1370x over previous
//
#include <hip/hip_runtime.h>
#include <math.h>

#define NEGF (-1e9f)

constexpr int NT = 1024;             // tokens
constexpr int D  = 768;
constexpr int SW = 30;               // max span width
constexpr int NC = NT * SW;          // 30720 candidates
constexpr int FT = 20;
constexpr int FF = 1000;
constexpr int TOPN = 409;            // int(0.4*1024)
constexpr int KA = 50;
constexpr int SD = 2 * D + FT + D;   // 2324
constexpr int MP = TOPN * KA;        // 20450
constexpr int MPP = 20480;           // MP padded to 128
constexpr int KP = 2336;             // SD padded to mult of 32
constexpr int NKT = KP / 32;         // 73
constexpr int CHPR = KP / 8;         // 292 chunks per row

typedef short short8 __attribute__((ext_vector_type(8)));
typedef float f32x4 __attribute__((ext_vector_type(4)));

// ---- ws layout (float units) ----
constexpr size_t al8(size_t x) { return (x + 7) & ~(size_t)7; }
constexpr size_t O_TOKATT = 0;                                     // 1024
constexpr size_t O_WPS    = al8(O_TOKATT + 1024);
constexpr size_t O_DPR    = al8(O_WPS + 32);
constexpr size_t O_MENT   = al8(O_DPR + 16);                       // NC
constexpr size_t O_TIDX   = al8(O_MENT + NC);                      // 512
constexpr size_t O_TST    = al8(O_TIDX + 512);
constexpr size_t O_TEN    = al8(O_TST + 512);
constexpr size_t O_TME    = al8(O_TEN + 512);
constexpr size_t O_TEMB   = al8(O_TME + 512);                      // 409*2324
constexpr size_t O_TMPB   = al8(O_TEMB + (size_t)TOPN * SD);       // 409*2325
constexpr size_t O_COARSE = al8(O_TMPB + (size_t)TOPN * (SD + 1)); // 409*409
constexpr size_t O_ANTI   = al8(O_COARSE + (size_t)TOPN * TOPN);   // 20480
constexpr size_t O_ANTC   = al8(O_ANTI + 20480);
constexpr size_t O_SLOW   = al8(O_ANTC + 20480);
constexpr size_t O_PALL   = al8(O_SLOW + 20480);                   // 24*1024
constexpr size_t O_HST    = al8(O_PALL + 24 * 1024);               // 512*2048
constexpr size_t O_TEMBH  = al8(O_HST + (size_t)512 * 2048);       // 512*KP bf16
constexpr size_t O_W1ST   = al8(O_TEMBH + (size_t)512 * KP / 2);   // 2048*KP bf16
constexpr size_t O_W1P    = al8(O_W1ST + (size_t)2048 * KP / 2);   // 1024*KP bf16
// E (1024*3072) and e2w (30*1024) are dead after k_ment; prodh aliases them.
constexpr size_t O_E      = al8(O_W1P + (size_t)1024 * KP / 2);
constexpr size_t O_E2W    = O_E + (size_t)NT * 3072;
constexpr size_t PRODH_F  = (size_t)MPP * KP / 2;                  // bf16 -> float units
constexpr size_t O_END_BIG   = O_E + PRODH_F;
constexpr size_t O_END_SMALL = O_E2W + 30 * 1024;

__device__ __forceinline__ unsigned int f2sort(float f) {
    unsigned int u = __float_as_uint(f);
    return (u & 0x80000000u) ? ~u : (u | 0x80000000u);
}
__device__ __forceinline__ float sort2f(unsigned int s) {
    return __uint_as_float((s & 0x80000000u) ? (s & 0x7FFFFFFFu) : ~s);
}
__device__ __forceinline__ int bucket_dist(int d) {   // d >= 0
    if (d <= 4) return d;
    return min(34 - __clz(d), 9);                     // floor(log2(d)) + 3, clipped
}
__device__ __forceinline__ unsigned short f2bf(float f) {   // RNE f32 -> bf16
    unsigned u = __float_as_uint(f);
    unsigned r = (u + 0x7fffu + ((u >> 16) & 1u)) >> 16;
    return (unsigned short)r;
}
__device__ __forceinline__ float bf2f(unsigned short s) {
    return __uint_as_float(((unsigned)s) << 16);
}

// ---------------- small prep kernels ----------------
__global__ void k_init(const float* b_p2, float* slow) {
    int i = blockIdx.x * 256 + threadIdx.x;
    if (i < MP) slow[i] = b_p2[0];
}

__global__ void k_zero(float* p, int n) {
    int i = blockIdx.x * 256 + threadIdx.x;
    if (i < n) p[i] = 0.f;
}
__global__ void k_zero4(float* p, int n4) {
    int i = blockIdx.x * 256 + threadIdx.x;
    if (i < n4) ((float4*)p)[i] = make_float4(0.f, 0.f, 0.f, 0.f);
}

__global__ void k_tokatt(const float* emb, const float* w, const float* b, float* out) {
    int wave = threadIdx.x >> 6, lane = threadIdx.x & 63;
    int tok = blockIdx.x * 4 + wave;
    float s = 0.f;
    for (int d = lane; d < D; d += 64) s += emb[tok * D + d] * w[d];
    for (int o = 32; o; o >>= 1) s += __shfl_down(s, o);
    if (lane == 0) out[tok] = s + b[0];
}

__global__ void k_widthps(const float* e, const float* w1, const float* b1,
                          const float* w2, const float* b2, float* out) {
    int wi = blockIdx.x;
    float acc = 0.f;
    for (int n = threadIdx.x; n < FF; n += 256) {
        float h = b1[n];
        for (int f = 0; f < FT; ++f) h += e[wi * FT + f] * w1[f * FF + n];
        acc += fmaxf(h, 0.f) * w2[n];
    }
    __shared__ float red[256];
    red[threadIdx.x] = acc; __syncthreads();
    for (int s = 128; s; s >>= 1) {
        if (threadIdx.x < s) red[threadIdx.x] += red[threadIdx.x + s];
        __syncthreads();
    }
    if (threadIdx.x == 0) out[wi] = red[0] + b2[0];
}

__global__ void k_distpr(const float* e, const float* w, const float* b, float* out) {
    int d = threadIdx.x;
    if (d < 10) {
        float s = b[0];
        for (int f = 0; f < FT; ++f) s += e[d * FT + f] * w[f];
        out[d] = s;
    }
}

// E2W[wd][n] = sum_f e_width[wd][f] * w_s1[(1536+f)][n]
__global__ void k_e2w(const float* ew, const float* w1, float* e2w) {
    int idx = blockIdx.x * 256 + threadIdx.x;
    if (idx >= 30 * 1024) return;
    int wd = idx >> 10, n = idx & 1023;
    float s = 0.f;
    if (n < FF) for (int f = 0; f < FT; ++f) s += ew[wd * FT + f] * w1[(2 * D + f) * FF + n];
    e2w[idx] = s;
}

// Pall rows: 0-1 same-speaker, 2 genre + b_p1, 3..13 seg-dist, 14..23 ant-dist
__global__ void k_prep_pall(const float* w1, const float* b1, const int* genre,
                            const float* e_same, const float* e_genre,
                            const float* e_seg, const float* e_antd, float* pall) {
    int idx = blockIdx.x * 256 + threadIdx.x;
    if (idx >= 24 * 1024) return;
    int r = idx >> 10, n = idx & 1023;
    float s = 0.f;
    if (n < FF) {
        const float* tab; int foff;
        if (r < 2)       { tab = e_same + r * FT;          foff = 0; }
        else if (r == 2) { tab = e_genre + genre[0] * FT;  foff = FT; s = b1[n]; }
        else if (r < 14) { tab = e_seg + (r - 3) * FT;     foff = 2 * FT; }
        else             { tab = e_antd + (r - 14) * FT;   foff = 3 * FT; }
        for (int f = 0; f < FT; ++f) s += tab[f] * w1[(size_t)(3 * SD + foff + f) * FF + n];
    }
    pall[idx] = s;
}

// temb (fp32, 409xSD) -> tembh (bf16, 512xKP, zero-padded)
__global__ void k_cvt_temb(const float* temb, unsigned short* tembh) {
    int idx = blockIdx.x * 256 + threadIdx.x;
    if (idx >= 512 * KP) return;
    int t = idx / KP, k = idx % KP;
    float v = (t < TOPN && k < SD) ? temb[(size_t)t * SD + k] : 0.f;
    tembh[idx] = f2bf(v);
}

// w_p1 slices -> transposed bf16 [RN][KP]. mode 0: RN=2048 (src|tgt halves); mode 1: RN=1024 (prod)
__global__ void k_cvt_w1(const float* w1, unsigned short* dst, int mode) {
    __shared__ float tile[32][33];
    int kp0 = blockIdx.x * 32;
    int r0  = blockIdx.y * 32;
    int tx = threadIdx.x & 31, ty = threadIdx.x >> 5;
    for (int i = 0; i < 4; ++i) {
        int r = r0 + tx, kp = kp0 + ty + i * 8;
        int c, ro;
        if (mode == 0) { c = r & 1023; ro = (r >> 10) * SD; }
        else           { c = r;        ro = 2 * SD; }
        float v = (c < FF && kp < SD) ? w1[(size_t)(ro + kp) * FF + c] : 0.f;
        tile[ty + i * 8][tx] = v;
    }
    __syncthreads();
    for (int i = 0; i < 4; ++i) {
        int r = r0 + ty + i * 8, kp = kp0 + tx;
        dst[(size_t)r * KP + kp] = f2bf(tile[tx][ty + i * 8]);
    }
}

// prodh[m] = tembh[t] * tembh[a]  (bf16 elementwise, RNE)
__global__ void k_prod(const unsigned short* __restrict__ tembh, const int* __restrict__ anti,
                       unsigned short* __restrict__ prodh) {
    int idx = blockIdx.x * 256 + threadIdx.x;
    if (idx >= MP * CHPR) return;
    int m = idx / CHPR;
    int ch = idx - m * CHPR;
    int t = m / KA;
    int a = anti[m];
    short8 x = *(const short8*)(tembh + (size_t)t * KP + ch * 8);
    short8 y = *(const short8*)(tembh + (size_t)a * KP + ch * 8);
    short8 o;
    #pragma unroll
    for (int e = 0; e < 8; ++e)
        o[e] = (short)f2bf(bf2f((unsigned short)x[e]) * bf2f((unsigned short)y[e]));
    *(short8*)(prodh + (size_t)m * KP + ch * 8) = o;
}

// ---------------- mention scores: per-start block, incremental attention ----------------
__global__ __launch_bounds__(256) void k_ment(
    const float* __restrict__ E, const float* __restrict__ e2w,
    const float* __restrict__ tokatt, const int* __restrict__ sentmap,
    const float* __restrict__ b1, const float* __restrict__ w2,
    const float* __restrict__ wps, const float* __restrict__ b_s2, float* ment) {
    int st = blockIdx.x;
    __shared__ float earr[32];
    __shared__ int vmask[32];
    __shared__ float swred[4][32];
    int tid = threadIdx.x;
    if (tid < SW) {
        int en = st + tid;
        bool ok = en < NT;
        earr[tid] = ok ? expf(tokatt[en]) : 0.f;
        vmask[tid] = ok && (sentmap[st] == sentmap[en]);
    }
    __syncthreads();
    int n4 = tid * 4;
    bool act = n4 < FF;
    float4 Es = {0,0,0,0}, B1 = {0,0,0,0}, W2 = {0,0,0,0};
    if (act) {
        Es = *(const float4*)(E + (size_t)st * 3072 + n4);
        B1 = *(const float4*)(b1 + n4);
        W2 = *(const float4*)(w2 + n4);
    }
    float Ux = 0, Uy = 0, Uz = 0, Uw = 0, S = 0.f;
    float part[SW];
    #pragma unroll
    for (int wd = 0; wd < SW; ++wd) {
        int en = st + wd;
        float p = 0.f;
        if (en < NT) {
            float e = earr[wd]; S += e;
            if (act) {
                float4 Eh = *(const float4*)(E + (size_t)en * 3072 + 2048 + n4);
                Ux += e * Eh.x; Uy += e * Eh.y; Uz += e * Eh.z; Uw += e * Eh.w;
                if (vmask[wd]) {
                    float inv = 1.f / S;
                    float4 Ee = *(const float4*)(E + (size_t)en * 3072 + 1024 + n4);
                    float4 Ww = *(const float4*)(e2w + wd * 1024 + n4);
                    float vx = Es.x + Ee.x + Ww.x + B1.x + Ux * inv;
                    float vy = Es.y + Ee.y + Ww.y + B1.y + Uy * inv;
                    float vz = Es.z + Ee.z + Ww.z + B1.z + Uz * inv;
                    float vw = Es.w + Ee.w + Ww.w + B1.w + Uw * inv;
                    p = fmaxf(vx, 0.f) * W2.x + fmaxf(vy, 0.f) * W2.y
                      + fmaxf(vz, 0.f) * W2.z + fmaxf(vw, 0.f) * W2.w;
                }
            }
        }
        part[wd] = p;
    }
    int lane = tid & 63, wv = tid >> 6;
    #pragma unroll
    for (int wd = 0; wd < SW; ++wd) {
        float r = part[wd];
        r += __shfl_xor(r, 1);  r += __shfl_xor(r, 2);  r += __shfl_xor(r, 4);
        r += __shfl_xor(r, 8);  r += __shfl_xor(r, 16); r += __shfl_xor(r, 32);
        if (lane == 0) swred[wv][wd] = r;
    }
    __syncthreads();
    if (tid < SW) {
        float tot = swred[0][tid] + swred[1][tid] + swred[2][tid] + swred[3][tid];
        ment[st * SW + tid] = vmask[tid] ? (tot + wps[tid] + b_s2[0]) : NEGF;
    }
}

// ---------------- top-409: radix-select + segment compaction + rank merge ----------------
__global__ __launch_bounds__(1024) void k_topk(const float* ment, int* topidx) {
    __shared__ unsigned int hist[256];
    __shared__ unsigned int sc[1024];
    __shared__ int lA[512], lB[512];
    __shared__ unsigned int sh_prefix, sh_needed;
    int tid = threadIdx.x;
    if (tid == 0) { sh_prefix = 0; sh_needed = TOPN; }
    for (int rd = 3; rd >= 0; --rd) {
        if (tid < 256) hist[tid] = 0;
        __syncthreads();
        unsigned pref = sh_prefix;
        for (int c = tid; c < NC; c += 1024) {
            unsigned u = f2sort(ment[c]);
            bool match = (rd == 3) || ((u >> ((rd + 1) * 8)) == pref);
            if (match) atomicAdd(&hist[(u >> (rd * 8)) & 255u], 1u);
        }
        __syncthreads();
        if (tid == 0) {
            unsigned need = sh_needed, cum = 0; int sel = 0;
            for (int b = 255; b >= 0; --b) {
                if (cum + hist[b] >= need) { sel = b; sh_needed = need - cum; break; }
                cum += hist[b];
            }
            sh_prefix = (sh_prefix << 8) | (unsigned)sel;
        }
        __syncthreads();
    }
    unsigned kth = sh_prefix;
    int quota = (int)sh_needed;
    // per-thread segment: 30 candidates each, ascending-index order preserved
    int base = tid * 30;
    int cgt = 0, ceq = 0;
    for (int j = 0; j < 30; ++j) {
        unsigned uu = f2sort(ment[base + j]);
        cgt += (uu > kth); ceq += (uu == kth);
    }
    // scan 1: strictly-greater counts
    sc[tid] = (unsigned)cgt; __syncthreads();
    for (int off = 1; off < 1024; off <<= 1) {
        unsigned v = (tid >= off) ? sc[tid - off] : 0u;
        __syncthreads(); sc[tid] += v; __syncthreads();
    }
    int egt = (int)sc[tid] - cgt;
    int nA = (int)sc[1023];
    int p = egt;
    for (int j = 0; j < 30; ++j) {
        int c = base + j;
        if (f2sort(ment[c]) > kth) lA[p++] = c;
    }
    __syncthreads();
    // scan 2: tie counts
    sc[tid] = (unsigned)ceq; __syncthreads();
    for (int off = 1; off < 1024; off <<= 1) {
        unsigned v = (tid >= off) ? sc[tid - off] : 0u;
        __syncthreads(); sc[tid] += v; __syncthreads();
    }
    int eeq = (int)sc[tid] - ceq;
    p = eeq;
    for (int j = 0; j < 30; ++j) {
        int c = base + j;
        if (f2sort(ment[c]) == kth) { if (p < quota) lB[p] = c; p++; }
    }
    __syncthreads();
    // rank-merge two ascending lists (disjoint values)
    if (tid < TOPN) {
        int v, rank;
        if (tid < nA) {
            v = lA[tid];
            int lo = 0, hi = quota;
            while (lo < hi) { int mid = (lo + hi) >> 1; if (lB[mid] < v) lo = mid + 1; else hi = mid; }
            rank = tid + lo;
        } else {
            int j = tid - nA;
            v = lB[j];
            int lo = 0, hi = nA;
            while (lo < hi) { int mid = (lo + hi) >> 1; if (lA[mid] < v) lo = mid + 1; else hi = mid; }
            rank = j + lo;
        }
        topidx[rank] = v;
    }
}

// gather top spans; computes head-attn emb on the fly
__global__ void k_gather(const float* emb, const float* wemb, const float* tokatt,
                         const float* ment, const int* topidx,
                         int* tst, int* ten, float* tme, float* temb,
                         float* out_s, float* out_e) {
    int t = blockIdx.x;
    int c = topidx[t];
    int st = c / SW, wd = c % SW;
    int en = min(st + wd, NT - 1);
    int len = en - st + 1;
    __shared__ float p[32];
    if (threadIdx.x == 0) {
        float m = -1e30f;
        for (int j = 0; j < len; ++j) m = fmaxf(m, tokatt[st + j]);
        float s = 0.f;
        for (int j = 0; j < len; ++j) { p[j] = expf(tokatt[st + j] - m); s += p[j]; }
        float inv = 1.f / s;
        for (int j = 0; j < len; ++j) p[j] *= inv;
        tst[t] = st; ten[t] = en; tme[t] = ment[c];
        out_s[t] = (float)st; out_e[t] = (float)en;
    }
    __syncthreads();
    for (int k = threadIdx.x; k < SD; k += 256) {
        float val;
        if (k < D) val = emb[st * D + k];
        else if (k < 2 * D) val = emb[en * D + (k - D)];
        else if (k < 2 * D + FT) val = wemb[wd * FT + (k - 2 * D)];
        else {
            int d = k - 2 * D - FT;
            float a = 0.f;
            for (int j = 0; j < len; ++j) a += p[j] * emb[(st + j) * D + d];
            val = a;
        }
        temb[(size_t)t * SD + k] = val;
    }
}

// ---------------- fp32 split-K GEMM: C[M,N] += A[M,K] @ B ----------------
template<int BT>
__global__ __launch_bounds__(256) void k_sgemm(
    const float* __restrict__ A, const float* __restrict__ B, float* __restrict__ C,
    int M, int N, int K, int lda, int ldb, int ldc, int kch) {
    int m0 = blockIdx.x * 64, n0 = blockIdx.y * 64;
    int kbeg = blockIdx.z * kch;
    int kend = min(K, kbeg + kch);
    __shared__ float As[32][68], Bs[32][68];
    int tid = threadIdx.x, tx = tid & 15, ty = tid >> 4;
    float acc[4][4] = {};
    float ra[8], rb[8];

    auto loadA = [&](int k0) {
        #pragma unroll
        for (int i = 0; i < 8; ++i) {
            int lid = tid + i * 256;
            int rr = lid >> 5, kk = lid & 31;
            int m = m0 + rr, k = k0 + kk;
            ra[i] = (m < M && k < kend) ? A[(size_t)m * lda + k] : 0.f;
        }
    };
    auto loadB = [&](int k0) {
        #pragma unroll
        for (int i = 0; i < 8; ++i) {
            int lid = tid + i * 256;
            if (BT) {
                int y = lid >> 5, kk = lid & 31;
                int n = n0 + y, k = k0 + kk;
                rb[i] = (n < N && k < kend) ? B[(size_t)n * ldb + k] : 0.f;
            } else {
                int rr = lid >> 6, nn = lid & 63;
                int k = k0 + rr, n = n0 + nn;
                rb[i] = (k < kend && n < N) ? B[(size_t)k * ldb + n] : 0.f;
            }
        }
    };

    loadA(kbeg); loadB(kbeg);
    for (int k0 = kbeg; k0 < kend; k0 += 32) {
        __syncthreads();
        float sa[8], sb[8];
        #pragma unroll
        for (int i = 0; i < 8; ++i) { sa[i] = ra[i]; sb[i] = rb[i]; }
        #pragma unroll
        for (int i = 0; i < 8; ++i) {
            int lid = tid + i * 256;
            As[lid & 31][lid >> 5] = sa[i];
            if (BT) Bs[lid & 31][lid >> 5] = sb[i];
            else    Bs[lid >> 6][lid & 63] = sb[i];
        }
        __syncthreads();
        if (k0 + 32 < kend) { loadA(k0 + 32); loadB(k0 + 32); }
        #pragma unroll
        for (int kk = 0; kk < 32; ++kk) {
            float4 a = *(const float4*)&As[kk][ty * 4];
            float4 b = *(const float4*)&Bs[kk][tx * 4];
            acc[0][0] += a.x * b.x; acc[0][1] += a.x * b.y; acc[0][2] += a.x * b.z; acc[0][3] += a.x * b.w;
            acc[1][0] += a.y * b.x; acc[1][1] += a.y * b.y; acc[1][2] += a.y * b.z; acc[1][3] += a.y * b.w;
            acc[2][0] += a.z * b.x; acc[2][1] += a.z * b.y; acc[2][2] += a.z * b.z; acc[2][3] += a.z * b.w;
            acc[3][0] += a.w * b.x; acc[3][1] += a.w * b.y; acc[3][2] += a.w * b.z; acc[3][3] += a.w * b.w;
        }
    }
    #pragma unroll
    for (int i = 0; i < 4; ++i)
        #pragma unroll
        for (int j = 0; j < 4; ++j) {
            int m = m0 + ty * 4 + i, n = n0 + tx * 4 + j;
            if (m < M && n < N) atomicAdd(&C[(size_t)m * ldc + n], acc[i][j]);
        }
}

// coarse base: bias col + ment sums + mask + dist prior
__global__ void k_initco(const float* tmpb, const float* tme, const float* dpr, float* coarse) {
    int idx = blockIdx.x * 256 + threadIdx.x;
    if (idx >= TOPN * TOPN) return;
    int x = idx / TOPN, y = idx - x * TOPN;
    int off = x - y;
    coarse[idx] = tmpb[(size_t)x * (SD + 1) + SD] + tme[x] + tme[y]
                + ((off >= 1) ? 0.f : NEGF) + dpr[bucket_dist(max(off, 0))];
}

// per-row top-50, 1 wave per row, packed keys in registers
__global__ __launch_bounds__(256) void k_topant(const float* coarse, int* anti,
                                                float* antc, float* out_ai) {
    int x = blockIdx.x * 4 + (threadIdx.x >> 6);
    int lane = threadIdx.x & 63;
    if (x >= TOPN) return;
    unsigned long long pk[8];
    #pragma unroll
    for (int j = 0; j < 8; ++j) {
        int y = lane + 64 * j;
        pk[j] = (y < TOPN)
              ? (((unsigned long long)f2sort(coarse[(size_t)x * TOPN + y]) << 32)
                 | (unsigned long long)(0xFFFFFFFFu - (unsigned)y))
              : 0ull;
    }
    for (int it = 0; it < KA; ++it) {
        unsigned long long best = 0ull;
        #pragma unroll
        for (int j = 0; j < 8; ++j) if (pk[j] > best) best = pk[j];
        #pragma unroll
        for (int o = 32; o; o >>= 1) {
            unsigned long long q = __shfl_xor(best, o);
            if (q > best) best = q;
        }
        int y = (int)(0xFFFFFFFFu - (unsigned)(best & 0xFFFFFFFFu));
        if (lane == 0) {
            anti[x * KA + it] = y;
            antc[x * KA + it] = sort2f((unsigned)(best >> 32));
            out_ai[x * KA + it] = (float)y;
        }
        if (lane == (y & 63)) {
            int jc = y >> 6;
            #pragma unroll
            for (int j = 0; j < 8; ++j) if (j == jc) pk[j] = 0ull;
        }
    }
}

// ---------------- bf16 MFMA GEMM, plain row-major A/B with K-stride KP ----------------
// MODE 0: A=tembh, B=w1st, writes Hst[512][2048]. MODE 1: A=prodh, B=w1p, fused epilogue -> slow.
template<int MODE>
__global__ __launch_bounds__(256) void k_mmp(
    const unsigned short* __restrict__ Ap, const unsigned short* __restrict__ w1t,
    const int* __restrict__ anti, const int* __restrict__ tstv,
    const int* __restrict__ spk, const int* __restrict__ seg,
    const float* __restrict__ Hst, const float* __restrict__ Pall,
    const float* __restrict__ w2, float* __restrict__ outp) {
    __shared__ unsigned short As[128 * 40];
    __shared__ unsigned short Bs[128 * 40];
    const int tid = threadIdx.x;
    const int n0 = blockIdx.x * 128, m0 = blockIdx.y * 128;
    const int l = tid & 63, wv = tid >> 6, wr = wv >> 1, wc = wv & 1;
    const int r = tid >> 1, h = tid & 1;

    const unsigned short* pa = Ap + (size_t)(m0 + r) * KP + h * 16;
    const unsigned short* pb = w1t + (size_t)(n0 + r) * KP + h * 16;
    unsigned short* awr = As + r * 40 + h * 16;
    unsigned short* bwr = Bs + r * 40 + h * 16;

    short8 ra0, ra1, rc0, rc1;
    ra0 = *(const short8*)(pa); ra1 = *(const short8*)(pa + 8);
    rc0 = *(const short8*)(pb); rc1 = *(const short8*)(pb + 8);

    f32x4 acc[4][4];
    #pragma unroll
    for (int i = 0; i < 4; ++i)
        #pragma unroll
        for (int j = 0; j < 4; ++j) acc[i][j] = (f32x4){0.f, 0.f, 0.f, 0.f};

    for (int kt = 0; kt < NKT; ++kt) {
        __syncthreads();
        *(short8*)(awr) = ra0; *(short8*)(awr + 8) = ra1;
        *(short8*)(bwr) = rc0; *(short8*)(bwr + 8) = rc1;
        __syncthreads();
        if (kt + 1 < NKT) {
            int ko = (kt + 1) * 32;
            ra0 = *(const short8*)(pa + ko); ra1 = *(const short8*)(pa + ko + 8);
            rc0 = *(const short8*)(pb + ko); rc1 = *(const short8*)(pb + ko + 8);
        }
        short8 af[4], bfr[4];
        #pragma unroll
        for (int mf = 0; mf < 4; ++mf)
            af[mf] = *(const short8*)(As + (wr * 64 + mf * 16 + (l & 15)) * 40 + (l >> 4) * 8);
        #pragma unroll
        for (int nf = 0; nf < 4; ++nf)
            bfr[nf] = *(const short8*)(Bs + (wc * 64 + nf * 16 + (l & 15)) * 40 + (l >> 4) * 8);
        #pragma unroll
        for (int mf = 0; mf < 4; ++mf)
            #pragma unroll
            for (int nf = 0; nf < 4; ++nf)
                acc[mf][nf] = __builtin_amdgcn_mfma_f32_16x16x32_bf16(af[mf], bfr[nf], acc[mf][nf], 0, 0, 0);
    }

    if (MODE == 0) {
        #pragma unroll
        for (int mf = 0; mf < 4; ++mf)
            #pragma unroll
            for (int nf = 0; nf < 4; ++nf)
                #pragma unroll
                for (int rg = 0; rg < 4; ++rg) {
                    int m = m0 + wr * 64 + mf * 16 + (l >> 4) * 4 + rg;
                    int n = n0 + wc * 64 + nf * 16 + (l & 15);
                    outp[(size_t)m * 2048 + n] = acc[mf][nf][rg];
                }
    } else {
        #pragma unroll
        for (int mf = 0; mf < 4; ++mf) {
            #pragma unroll
            for (int rg = 0; rg < 4; ++rg) {
                int m = m0 + wr * 64 + mf * 16 + (l >> 4) * 4 + rg;
                float ps = 0.f;
                if (m < MP) {
                    int t = m / KA; int a = anti[m];
                    int u1 = tstv[t], u2 = tstv[a];
                    const float* rs = Hst + (size_t)t * 2048;
                    const float* rt = Hst + (size_t)a * 2048 + 1024;
                    const float* q1 = Pall + ((spk[u1] == spk[u2]) ? 1 : 0) * 1024;
                    const float* q2 = Pall + 2 * 1024;
                    int sdv = seg[u1] - seg[u2]; sdv = min(max(sdv, 0), 10);
                    const float* q3 = Pall + (3 + sdv) * 1024;
                    const float* q4 = Pall + (14 + bucket_dist(max(t - a, 0))) * 1024;
                    #pragma unroll
                    for (int nf = 0; nf < 4; ++nf) {
                        int n = n0 + wc * 64 + nf * 16 + (l & 15);
                        if (n < FF) {
                            float v = acc[mf][nf][rg] + rs[n] + rt[n] + q1[n] + q2[n] + q3[n] + q4[n];
                            ps += fmaxf(v, 0.f) * w2[n];
                        }
                    }
                }
                ps += __shfl_xor(ps, 1); ps += __shfl_xor(ps, 2);
                ps += __shfl_xor(ps, 4); ps += __shfl_xor(ps, 8);
                if ((l & 15) == 0 && m < MP) atomicAdd(&outp[m], ps);
            }
        }
    }
}

// fallback: on-the-fly product GEMM (round-4 kernel, MODE1 semantics)
__global__ __launch_bounds__(256) void k_mm_fly(
    const unsigned short* __restrict__ tembh, const unsigned short* __restrict__ w1t,
    const int* __restrict__ anti, const int* __restrict__ tstv,
    const int* __restrict__ spk, const int* __restrict__ seg,
    const float* __restrict__ Hst, const float* __restrict__ Pall,
    const float* __restrict__ w2, float* __restrict__ outp) {
    __shared__ unsigned short As[128 * 40];
    __shared__ unsigned short Bs[128 * 40];
    const int tid = threadIdx.x;
    const int m0 = blockIdx.x * 128, n0 = blockIdx.y * 128;
    const int l = tid & 63, wv = tid >> 6, wr = wv >> 1, wc = wv & 1;
    const int r = tid >> 1, h = tid & 1;

    const unsigned short *pa0, *pa1;
    bool za = false;
    {
        int m = m0 + r;
        if (m < MP) {
            int t = m / KA; int a = anti[m];
            pa0 = tembh + (size_t)t * KP + h * 16;
            pa1 = tembh + (size_t)a * KP + h * 16;
        } else { za = true; pa0 = tembh; pa1 = tembh; }
    }
    const unsigned short* pb = w1t + (size_t)(n0 + r) * KP + h * 16;
    unsigned short* awr = As + r * 40 + h * 16;
    unsigned short* bwr = Bs + r * 40 + h * 16;

    short8 ra0, ra1, rb0, rb1, rc0, rc1;
    ra0 = *(const short8*)(pa0); ra1 = *(const short8*)(pa0 + 8);
    rb0 = *(const short8*)(pa1); rb1 = *(const short8*)(pa1 + 8);
    rc0 = *(const short8*)(pb);  rc1 = *(const short8*)(pb + 8);

    f32x4 acc[4][4];
    #pragma unroll
    for (int i = 0; i < 4; ++i)
        #pragma unroll
        for (int j = 0; j < 4; ++j) acc[i][j] = (f32x4){0.f, 0.f, 0.f, 0.f};

    for (int kt = 0; kt < NKT; ++kt) {
        __syncthreads();
        short8 wa0, wa1;
        #pragma unroll
        for (int e = 0; e < 8; ++e) {
            float x0 = bf2f((unsigned short)ra0[e]) * bf2f((unsigned short)rb0[e]);
            float x1 = bf2f((unsigned short)ra1[e]) * bf2f((unsigned short)rb1[e]);
            wa0[e] = za ? (short)0 : (short)f2bf(x0);
            wa1[e] = za ? (short)0 : (short)f2bf(x1);
        }
        *(short8*)(awr) = wa0; *(short8*)(awr + 8) = wa1;
        *(short8*)(bwr) = rc0; *(short8*)(bwr + 8) = rc1;
        __syncthreads();
        if (kt + 1 < NKT) {
            int ko = (kt + 1) * 32;
            ra0 = *(const short8*)(pa0 + ko); ra1 = *(const short8*)(pa0 + ko + 8);
            rb0 = *(const short8*)(pa1 + ko); rb1 = *(const short8*)(pa1 + ko + 8);
            rc0 = *(const short8*)(pb + ko);  rc1 = *(const short8*)(pb + ko + 8);
        }
        short8 af[4], bfr[4];
        #pragma unroll
        for (int mf = 0; mf < 4; ++mf)
            af[mf] = *(const short8*)(As + (wr * 64 + mf * 16 + (l & 15)) * 40 + (l >> 4) * 8);
        #pragma unroll
        for (int nf = 0; nf < 4; ++nf)
            bfr[nf] = *(const short8*)(Bs + (wc * 64 + nf * 16 + (l & 15)) * 40 + (l >> 4) * 8);
        #pragma unroll
        for (int mf = 0; mf < 4; ++mf)
            #pragma unroll
            for (int nf = 0; nf < 4; ++nf)
                acc[mf][nf] = __builtin_amdgcn_mfma_f32_16x16x32_bf16(af[mf], bfr[nf], acc[mf][nf], 0, 0, 0);
    }
    #pragma unroll
    for (int mf = 0; mf < 4; ++mf) {
        #pragma unroll
        for (int rg = 0; rg < 4; ++rg) {
            int m = m0 + wr * 64 + mf * 16 + (l >> 4) * 4 + rg;
            float ps = 0.f;
            if (m < MP) {
                int t = m / KA; int a = anti[m];
                int u1 = tstv[t], u2 = tstv[a];
                const float* rs = Hst + (size_t)t * 2048;
                const float* rt = Hst + (size_t)a * 2048 + 1024;
                const float* q1 = Pall + ((spk[u1] == spk[u2]) ? 1 : 0) * 1024;
                const float* q2 = Pall + 2 * 1024;
                int sdv = seg[u1] - seg[u2]; sdv = min(max(sdv, 0), 10);
                const float* q3 = Pall + (3 + sdv) * 1024;
                const float* q4 = Pall + (14 + bucket_dist(max(t - a, 0))) * 1024;
                #pragma unroll
                for (int nf = 0; nf < 4; ++nf) {
                    int n = n0 + wc * 64 + nf * 16 + (l & 15);
                    if (n < FF) {
                        float v = acc[mf][nf][rg] + rs[n] + rt[n] + q1[n] + q2[n] + q3[n] + q4[n];
                        ps += fmaxf(v, 0.f) * w2[n];
                    }
                }
            }
            ps += __shfl_xor(ps, 1); ps += __shfl_xor(ps, 2);
            ps += __shfl_xor(ps, 4); ps += __shfl_xor(ps, 8);
            if ((l & 15) == 0 && m < MP) atomicAdd(&outp[m], ps);
        }
    }
}

__global__ void k_final(const int* anti, const float* slow, const float* antc, float* out_f) {
    int t = blockIdx.x, j = threadIdx.x;
    if (j < KA) {
        int a = anti[t * KA + j];
        float sc = (a < t) ? (slow[t * KA + j] + antc[t * KA + j]) : NEGF;
        out_f[t * (KA + 1) + 1 + j] = sc;
    }
    if (j == KA) out_f[t * (KA + 1)] = 0.f;
}

extern "C" void kernel_launch(void* const* d_in, const int* in_sizes, int n_in,
                              void* d_out, int out_size, void* d_ws, size_t ws_size,
                              hipStream_t stream) {
    const float* token_embs = (const float*)d_in[0];
    const int*   speaker    = (const int*)d_in[1];
    const int*   sentmap    = (const int*)d_in[2];
    const int*   segids     = (const int*)d_in[3];
    const int*   genre      = (const int*)d_in[4];
    const float* e_width    = (const float*)d_in[5];
    const float* e_width_pr = (const float*)d_in[6];
    const float* w_matt     = (const float*)d_in[7];
    const float* b_matt     = (const float*)d_in[8];
    const float* w_s1       = (const float*)d_in[9];
    const float* b_s1       = (const float*)d_in[10];
    const float* w_s2       = (const float*)d_in[11];
    const float* b_s2       = (const float*)d_in[12];
    const float* w_w1       = (const float*)d_in[13];
    const float* b_w1       = (const float*)d_in[14];
    const float* w_w2       = (const float*)d_in[15];
    const float* b_w2       = (const float*)d_in[16];
    const float* w_bi       = (const float*)d_in[17];
    const float* e_adp      = (const float*)d_in[18];
    const float* w_ad       = (const float*)d_in[19];
    const float* b_ad       = (const float*)d_in[20];
    const float* e_same     = (const float*)d_in[21];
    const float* e_genre    = (const float*)d_in[22];
    const float* e_seg      = (const float*)d_in[23];
    const float* e_antd     = (const float*)d_in[24];
    const float* w_p1       = (const float*)d_in[25];
    const float* b_p1       = (const float*)d_in[26];
    const float* w_p2       = (const float*)d_in[27];
    const float* b_p2       = (const float*)d_in[28];

    float* F = (float*)d_ws;
    float* tokatt = F + O_TOKATT;
    float* wps    = F + O_WPS;
    float* dpr    = F + O_DPR;
    float* ment   = F + O_MENT;
    int*   tidx   = (int*)(F + O_TIDX);
    int*   tst    = (int*)(F + O_TST);
    int*   ten    = (int*)(F + O_TEN);
    float* tme    = F + O_TME;
    float* temb   = F + O_TEMB;
    float* tmpb   = F + O_TMPB;
    float* coarse = F + O_COARSE;
    int*   anti   = (int*)(F + O_ANTI);
    float* antc   = F + O_ANTC;
    float* slow   = F + O_SLOW;
    float* pall   = F + O_PALL;
    float* hst    = F + O_HST;
    unsigned short* tembh = (unsigned short*)(F + O_TEMBH);
    unsigned short* w1st  = (unsigned short*)(F + O_W1ST);
    unsigned short* w1p   = (unsigned short*)(F + O_W1P);
    float* E      = F + O_E;
    float* e2w    = F + O_E2W;
    unsigned short* prodh = (unsigned short*)(F + O_E);   // aliases E (dead by then)

    bool big = ws_size >= O_END_BIG * sizeof(float);

    float* out    = (float*)d_out;
    float* out_s  = out;
    float* out_e  = out + TOPN;
    float* out_ai = out + 2 * TOPN;
    float* out_f  = out + 2 * TOPN + MP;

    // weight-only prep
    k_init<<<(MP + 255) / 256, 256, 0, stream>>>(b_p2, slow);
    k_cvt_w1<<<dim3(NKT, 64), 256, 0, stream>>>(w_p1, w1st, 0);
    k_cvt_w1<<<dim3(NKT, 32), 256, 0, stream>>>(w_p1, w1p, 1);
    k_prep_pall<<<(24 * 1024 + 255) / 256, 256, 0, stream>>>(w_p1, b_p1, genre,
                                                             e_same, e_genre, e_seg, e_antd, pall);
    k_tokatt<<<NT / 4, 256, 0, stream>>>(token_embs, w_matt, b_matt, tokatt);
    k_widthps<<<SW, 256, 0, stream>>>(e_width_pr, w_w1, b_w1, w_w2, b_w2, wps);
    k_distpr<<<1, 64, 0, stream>>>(e_adp, w_ad, b_ad, dpr);

    // E = emb @ W1-slices (start|end|head), fp32 split-K
    k_zero4<<<(NT * 3072 / 4 + 255) / 256, 256, 0, stream>>>(E, NT * 3072 / 4);
    {
        dim3 g(NT / 64, (FF + 63) / 64, 2);
        k_sgemm<0><<<g, 256, 0, stream>>>(token_embs, w_s1,                 E,        NT, FF, D, D, FF, 3072, 384);
        k_sgemm<0><<<g, 256, 0, stream>>>(token_embs, w_s1 + D * FF,        E + 1024, NT, FF, D, D, FF, 3072, 384);
        k_sgemm<0><<<g, 256, 0, stream>>>(token_embs, w_s1 + (2*D+FT) * FF, E + 2048, NT, FF, D, D, FF, 3072, 384);
    }
    k_e2w<<<(30 * 1024 + 255) / 256, 256, 0, stream>>>(e_width, w_s1, e2w);

    k_ment<<<NT, 256, 0, stream>>>(E, e2w, tokatt, sentmap, b_s1, w_s2, wps, b_s2, ment);
    k_topk<<<1, 1024, 0, stream>>>(ment, tidx);
    k_gather<<<TOPN, 256, 0, stream>>>(token_embs, e_width, tokatt, ment, tidx,
                                       tst, ten, tme, temb, out_s, out_e);
    k_cvt_temb<<<(512 * KP + 255) / 256, 256, 0, stream>>>(temb, tembh);

    // biaffine (fp32 split-K)
    k_zero<<<(TOPN * (SD + 1) + 255) / 256, 256, 0, stream>>>(tmpb, TOPN * (SD + 1));
    {
        dim3 g((TOPN + 63) / 64, (SD + 1 + 63) / 64, 4);
        k_sgemm<0><<<g, 256, 0, stream>>>(temb, w_bi, tmpb, TOPN, SD + 1, SD, SD, SD + 1, SD + 1, 608);
    }
    k_initco<<<(TOPN * TOPN + 255) / 256, 256, 0, stream>>>(tmpb, tme, dpr, coarse);
    {
        dim3 g((TOPN + 63) / 64, (TOPN + 63) / 64, 8);
        k_sgemm<1><<<g, 256, 0, stream>>>(tmpb, temb, coarse, TOPN, TOPN, SD, SD + 1, SD, TOPN, 320);
    }
    k_topant<<<(TOPN + 3) / 4, 256, 0, stream>>>(coarse, anti, antc, out_ai);

    // pair path (bf16 MFMA)
    k_mmp<0><<<dim3(16, 4), 256, 0, stream>>>(tembh, w1st, anti, tst, speaker, segids,
                                              hst, pall, w_p2, hst);
    if (big) {
        k_prod<<<(MP * CHPR + 255) / 256, 256, 0, stream>>>(tembh, anti, prodh);
        k_mmp<1><<<dim3(8, 160), 256, 0, stream>>>(prodh, w1p, anti, tst, speaker, segids,
                                                   hst, pall, w_p2, slow);
    } else {
        k_mm_fly<<<dim3(160, 8), 256, 0, stream>>>(tembh, w1p, anti, tst, speaker, segids,
                                                   hst, pall, w_p2, slow);
    }
    k_final<<<TOPN, 64, 0, stream>>>(anti, slow, antc, out_f);
}